// Round 7
// baseline (558.319 us; speedup 1.0000x reference)
//
#include <hip/hip_runtime.h>

#define N_NODES 100000
#define N_EDGES 3200000
#define F_IN    128
#define HC      32      // H*C
#define CH      16      // C per head
#define NGRAPH  64
#define NEG     0.2f

#define BSH   7                                   // 128 nodes per bucket
#define BNODE (1 << BSH)
#define NB2   ((N_NODES + BNODE - 1) >> BSH)      // 782 buckets
#define EPB3  32768                               // edges per k_bucket block

__device__ __forceinline__ float lrelu(float x) { return x > 0.f ? x : NEG * x; }

// ---------- fused: ea sum + bucket histogram (one edge stream) ----------

__global__ void k_pre(const float* __restrict__ ea, const int* __restrict__ dst,
                      float* __restrict__ params, int* __restrict__ cnt) {
    __shared__ int l[NB2];
    for (int i = threadIdx.x; i < NB2; i += 256) l[i] = 0;
    __syncthreads();
    float acc = 0.f;
    for (int e = blockIdx.x * blockDim.x + threadIdx.x; e < N_EDGES;
         e += gridDim.x * blockDim.x) {
        acc += ea[e];
        atomicAdd(&l[dst[e] >> BSH], 1);
    }
    for (int m = 32; m >= 1; m >>= 1) acc += __shfl_xor(acc, m, 64);
    __shared__ float sh[4];
    int lane = threadIdx.x & 63, wid = threadIdx.x >> 6;
    if (lane == 0) sh[wid] = acc;
    __syncthreads();
    if (threadIdx.x == 0)
        unsafeAtomicAdd(params, sh[0] + sh[1] + sh[2] + sh[3]);
    for (int i = threadIdx.x; i < NB2; i += 256)
        if (l[i]) atomicAdd(&cnt[i], l[i]);
}

// ---------- fused: params precompute + bucket scan (single block) ----------
// params: [0]=ea_sum, [1]=ea_mean, [2..3]=ce layer1, [4..5]=ce layer2

__global__ void k_setup(const float* __restrict__ We1, const float* __restrict__ ae1,
                        const float* __restrict__ We2, const float* __restrict__ ae2,
                        float* __restrict__ params, const int* __restrict__ cnt,
                        int* __restrict__ gstart, int* __restrict__ gcur,
                        int* __restrict__ rowptr) {
    int t = threadIdx.x;
    if (t < 2) {
        float c1 = 0.f, c2 = 0.f;
        for (int c = 0; c < CH; ++c) {
            c1 += We1[t * CH + c] * ae1[t * CH + c];
            c2 += We2[t * CH + c] * ae2[t * CH + c];
        }
        params[2 + t] = c1;
        params[4 + t] = c2;
        if (t == 0) params[1] = params[0] / (float)N_EDGES;
    }
    __shared__ int sh[256];
    int v[4];
    int s = 0;
    for (int j = 0; j < 4; ++j) {
        int i = t * 4 + j;
        v[j] = (i < NB2) ? cnt[i] : 0;
        s += v[j];
    }
    sh[t] = s;
    __syncthreads();
    for (int off = 1; off < 256; off <<= 1) {
        int u = (t >= off) ? sh[t - off] : 0;
        __syncthreads();
        sh[t] += u;
        __syncthreads();
    }
    int ex = sh[t] - s;   // exclusive prefix
    for (int j = 0; j < 4; ++j) {
        int i = t * 4 + j;
        if (i < NB2) { gstart[i] = ex; gcur[i] = ex; ex += v[j]; }
    }
    if (t == 255) {
        gstart[NB2] = N_EDGES;
        rowptr[N_NODES] = N_EDGES;
    }
}

// ---------- pass A: two-phase bucket scatter (32k edges/block, long runs) ----------

__global__ void k_bucket(const int* __restrict__ src, const int* __restrict__ dst,
                         const float* __restrict__ ea, int* __restrict__ gcur,
                         int2* __restrict__ staged) {
    __shared__ int lcnt[NB2];
    __shared__ int lbase[NB2];
    int t = threadIdx.x;
    for (int i = t; i < NB2; i += 256) lcnt[i] = 0;
    __syncthreads();
    int base = blockIdx.x * EPB3;
    int end = base + EPB3;
    if (end > N_EDGES) end = N_EDGES;
    for (int e = base + t; e < end; e += 256)
        atomicAdd(&lcnt[dst[e] >> BSH], 1);
    __syncthreads();
    for (int i = t; i < NB2; i += 256) {
        int c = lcnt[i];
        lbase[i] = (c > 0) ? atomicAdd(&gcur[i], c) : 0;
    }
    __syncthreads();
    for (int i = t; i < NB2; i += 256) lcnt[i] = 0;
    __syncthreads();
    for (int e = base + t; e < end; e += 256) {
        int dv = dst[e];
        int b = dv >> BSH;
        int r = atomicAdd(&lcnt[b], 1);
        staged[lbase[b] + r] =
            make_int2((src[e] << BSH) | (dv & (BNODE - 1)), __float_as_int(ea[e]));
    }
}

// ---------- pass B: per-bucket local hist+scan, write rowptr + per-node-sorted epack ----------

__global__ void k_scatter(const int2* __restrict__ staged, const int* __restrict__ gstart,
                          int* __restrict__ rowptr, int2* __restrict__ epack) {
    __shared__ int cntl[BNODE];
    __shared__ int scanb[BNODE];
    __shared__ int cur[BNODE];
    int b = blockIdx.x, t = threadIdx.x;
    int nbase = b << BSH;
    int bcount = N_NODES - nbase;
    if (bcount > BNODE) bcount = BNODE;
    if (t < BNODE) cntl[t] = 0;
    __syncthreads();
    int st = gstart[b], en = gstart[b + 1];
    for (int e = st + t; e < en; e += 256)
        atomicAdd(&cntl[staged[e].x & (BNODE - 1)], 1);
    __syncthreads();
    if (t < BNODE) scanb[t] = cntl[t];
    __syncthreads();
    for (int off = 1; off < BNODE; off <<= 1) {
        int u = (t < BNODE && t >= off) ? scanb[t - off] : 0;
        __syncthreads();
        if (t < BNODE) scanb[t] += u;
        __syncthreads();
    }
    if (t < BNODE) {
        int ex = st + scanb[t] - cntl[t];   // exclusive, global
        cur[t] = ex;
        if (t < bcount) rowptr[nbase + t] = ex;
    }
    __syncthreads();
    for (int e = st + t; e < en; e += 256) {
        int2 r = staged[e];
        int pos = atomicAdd(&cur[r.x & (BNODE - 1)], 1);
        epack[pos] = r;
    }
}

// ---------- dense: h = x @ W (LDS-tiled), plus fused asrc/adst ----------

#define COLS(ac, xv)                                                     \
    ac[0] = fmaf(xv.x, w0.x, ac[0]); ac[1] = fmaf(xv.x, w0.y, ac[1]);    \
    ac[2] = fmaf(xv.x, w0.z, ac[2]); ac[3] = fmaf(xv.x, w0.w, ac[3]);    \
    ac[0] = fmaf(xv.y, w1.x, ac[0]); ac[1] = fmaf(xv.y, w1.y, ac[1]);    \
    ac[2] = fmaf(xv.y, w1.z, ac[2]); ac[3] = fmaf(xv.y, w1.w, ac[3]);    \
    ac[0] = fmaf(xv.z, w2.x, ac[0]); ac[1] = fmaf(xv.z, w2.y, ac[1]);    \
    ac[2] = fmaf(xv.z, w2.z, ac[2]); ac[3] = fmaf(xv.z, w2.w, ac[3]);    \
    ac[0] = fmaf(xv.w, w3.x, ac[0]); ac[1] = fmaf(xv.w, w3.y, ac[1]);    \
    ac[2] = fmaf(xv.w, w3.z, ac[2]); ac[3] = fmaf(xv.w, w3.w, ac[3]);

template <int FIN>
__global__ __launch_bounds__(256)
void k_linear(const float* __restrict__ x, const float* __restrict__ W,
              const float* __restrict__ a_src, const float* __restrict__ a_dst,
              float* __restrict__ h, float* __restrict__ asrc,
              float* __restrict__ adst) {
    constexpr int PAD = FIN + 4;
    __shared__ float ws[FIN * HC];
    __shared__ float xs[64 * PAD];
    int t = threadIdx.x;
    int nbase = blockIdx.x * 64;
    int bcount = N_NODES - nbase;
    if (bcount > 64) bcount = 64;

    for (int i = t; i < FIN * HC / 4; i += 256)
        ((float4*)ws)[i] = ((const float4*)W)[i];
    const float4* xg = (const float4*)(x + (size_t)nbase * FIN);
    int nf4 = bcount * FIN / 4;
    for (int i = t; i < 64 * FIN / 4; i += 256) {
        if (i < nf4) {
            float4 v = xg[i];
            int flat = i * 4;
            int row = flat / FIN, col = flat % FIN;
            *(float4*)&xs[row * PAD + col] = v;
        }
    }
    __syncthreads();

    int cg = t & 7, np = t >> 3;
    int n0 = np * 2, n1 = n0 + 1;
    float acc0[4] = {0.f, 0.f, 0.f, 0.f};
    float acc1[4] = {0.f, 0.f, 0.f, 0.f};
#pragma unroll
    for (int k = 0; k < FIN; k += 4) {
        float4 xa = *(const float4*)&xs[n0 * PAD + k];
        float4 xb = *(const float4*)&xs[n1 * PAD + k];
        const float4* wp = (const float4*)&ws[k * HC] + cg;
        float4 w0 = wp[0], w1 = wp[8], w2 = wp[16], w3 = wp[24];
        COLS(acc0, xa)
        COLS(acc1, xb)
    }

    int hh = cg >> 2;
    float s0 = 0.f, d0 = 0.f, s1 = 0.f, d1 = 0.f;
#pragma unroll
    for (int j = 0; j < 4; ++j) {
        float av = a_src[hh * CH + (cg & 3) * 4 + j];
        float dv = a_dst[hh * CH + (cg & 3) * 4 + j];
        s0 = fmaf(acc0[j], av, s0); d0 = fmaf(acc0[j], dv, d0);
        s1 = fmaf(acc1[j], av, s1); d1 = fmaf(acc1[j], dv, d1);
    }
    s0 += __shfl_xor(s0, 1, 64); s0 += __shfl_xor(s0, 2, 64);
    d0 += __shfl_xor(d0, 1, 64); d0 += __shfl_xor(d0, 2, 64);
    s1 += __shfl_xor(s1, 1, 64); s1 += __shfl_xor(s1, 2, 64);
    d1 += __shfl_xor(d1, 1, 64); d1 += __shfl_xor(d1, 2, 64);

    if (n0 < bcount) {
        *(float4*)&h[(size_t)(nbase + n0) * HC + cg * 4] =
            make_float4(acc0[0], acc0[1], acc0[2], acc0[3]);
        if ((cg & 3) == 0) {
            asrc[(nbase + n0) * 2 + hh] = s0;
            adst[(nbase + n0) * 2 + hh] = d0;
        }
    }
    if (n1 < bcount) {
        *(float4*)&h[(size_t)(nbase + n1) * HC + cg * 4] =
            make_float4(acc1[0], acc1[1], acc1[2], acc1[3]);
        if ((cg & 3) == 0) {
            asrc[(nbase + n1) * 2 + hh] = s1;
            adst[(nbase + n1) * 2 + hh] = d1;
        }
    }
}

// ---------- fused GAT layer: 16 lanes/node, float2 channels, 4x unrolled ----------

__global__ void k_gat(const int* __restrict__ rowptr, const int2* __restrict__ epack,
                      const float* __restrict__ h,
                      const float* __restrict__ asrc, const float* __restrict__ adst,
                      const float* __restrict__ params, int ceoff,
                      const float* __restrict__ bias, int do_relu,
                      float* __restrict__ out) {
    int tid = blockIdx.x * blockDim.x + threadIdx.x;
    int n = tid >> 4;
    if (n >= N_NODES) return;
    int c2 = tid & 15, hh = c2 >> 3;       // channels 2*c2, 2*c2+1; head = c2>>3
    int st = rowptr[n], en = rowptr[n + 1];
    float ce = params[ceoff + hh];
    float adn = adst[n * 2 + hh];
    const float2* h2 = (const float2*)h;
    float ax = 0.f, ay = 0.f, ssum = 0.f;
    int e = st;
    for (; e + 3 < en; e += 4) {
        int2 r0 = epack[e], r1 = epack[e + 1], r2 = epack[e + 2], r3 = epack[e + 3];
        int s0 = r0.x >> BSH, s1 = r1.x >> BSH, s2 = r2.x >> BSH, s3 = r3.x >> BSH;
        float a0 = asrc[s0 * 2 + hh], a1 = asrc[s1 * 2 + hh];
        float a2 = asrc[s2 * 2 + hh], a3 = asrc[s3 * 2 + hh];
        float2 h0 = h2[s0 * 16 + c2], h1 = h2[s1 * 16 + c2];
        float2 hx2 = h2[s2 * 16 + c2], h3 = h2[s3 * 16 + c2];
        float w0 = __expf(lrelu(a0 + adn + ce * __int_as_float(r0.y)));
        float w1 = __expf(lrelu(a1 + adn + ce * __int_as_float(r1.y)));
        float w2 = __expf(lrelu(a2 + adn + ce * __int_as_float(r2.y)));
        float w3 = __expf(lrelu(a3 + adn + ce * __int_as_float(r3.y)));
        ax = fmaf(w0, h0.x, ax); ay = fmaf(w0, h0.y, ay); ssum += w0;
        ax = fmaf(w1, h1.x, ax); ay = fmaf(w1, h1.y, ay); ssum += w1;
        ax = fmaf(w2, hx2.x, ax); ay = fmaf(w2, hx2.y, ay); ssum += w2;
        ax = fmaf(w3, h3.x, ax); ay = fmaf(w3, h3.y, ay); ssum += w3;
    }
    for (; e < en; ++e) {
        int2 r = epack[e];
        int sv = r.x >> BSH;
        float asv = asrc[sv * 2 + hh];
        float2 hv = h2[sv * 16 + c2];
        float wv = __expf(lrelu(asv + adn + ce * __int_as_float(r.y)));
        ax = fmaf(wv, hv.x, ax); ay = fmaf(wv, hv.y, ay);
        ssum += wv;
    }
    // self-loop (eattr = mean)
    float wself = __expf(lrelu(asrc[n * 2 + hh] + adn + ce * params[1]));
    float2 hs = h2[n * 16 + c2];
    ax = fmaf(wself, hs.x, ax); ay = fmaf(wself, hs.y, ay);
    ssum += wself;
    float inv = 1.f / (ssum + 1e-16f);
    float2 bv = ((const float2*)bias)[c2];
    float vx = ax * inv + bv.x, vy = ay * inv + bv.y;
    if (do_relu) { vx = fmaxf(vx, 0.f); vy = fmaxf(vy, 0.f); }
    ((float2*)out)[n * 16 + c2] = make_float2(vx, vy);
}

// ---------- fused pooling (binary search on sorted batch) + MLP head ----------

__global__ void k_poolmlp(const float* __restrict__ feat, const int* __restrict__ batch,
                          const float* __restrict__ Wf1, const float* __restrict__ bf1,
                          const float* __restrict__ Wf2, const float* __restrict__ bf2,
                          float* __restrict__ out) {
    int g = blockIdx.x;
    __shared__ int sse[2];
    if (threadIdx.x < 2) {
        int target = g + (int)threadIdx.x;
        int lo = 0, hi = N_NODES;
        while (lo < hi) {
            int mid = (lo + hi) >> 1;
            if (batch[mid] < target) lo = mid + 1; else hi = mid;
        }
        sse[threadIdx.x] = lo;
    }
    __syncthreads();
    int st = sse[0], en = sse[1];
    int c = threadIdx.x & 31, r = threadIdx.x >> 5;  // r in 0..7
    float acc = 0.f;
    for (int n = st + r; n < en; n += 8) acc += feat[(size_t)n * HC + c];
    __shared__ float sh[8][32];
    sh[r][c] = acc;
    __syncthreads();
    __shared__ float emb[32];
    __shared__ float hid[32];
    if (threadIdx.x < 32) {
        float t = 0.f;
        for (int r2 = 0; r2 < 8; ++r2) t += sh[r2][c];
        int cnt = en - st;
        emb[c] = t / (float)(cnt > 0 ? cnt : 1);
    }
    __syncthreads();
    if (threadIdx.x < 32) {
        int j = threadIdx.x;
        float a = bf1[j];
        for (int k = 0; k < 32; ++k) a = fmaf(emb[k], Wf1[k * 32 + j], a);
        hid[j] = fmaxf(a, 0.f);
    }
    __syncthreads();
    if (threadIdx.x < 2) {
        int j = threadIdx.x;
        float o = bf2[j];
        for (int k = 0; k < 32; ++k) o = fmaf(hid[k], Wf2[k * 2 + j], o);
        out[g * 2 + j] = o;
    }
}

extern "C" void kernel_launch(void* const* d_in, const int* in_sizes, int n_in,
                              void* d_out, int out_size, void* d_ws, size_t ws_size,
                              hipStream_t stream) {
    const float* x   = (const float*)d_in[0];
    const int*   ei  = (const int*)d_in[1];
    const float* ea  = (const float*)d_in[2];
    const int* batch = (const int*)d_in[3];
    const float* W1  = (const float*)d_in[4];
    const float* as1 = (const float*)d_in[5];
    const float* ad1 = (const float*)d_in[6];
    const float* We1 = (const float*)d_in[7];
    const float* ae1 = (const float*)d_in[8];
    const float* b1  = (const float*)d_in[9];
    const float* W2  = (const float*)d_in[10];
    const float* as2 = (const float*)d_in[11];
    const float* ad2 = (const float*)d_in[12];
    const float* We2 = (const float*)d_in[13];
    const float* ae2 = (const float*)d_in[14];
    const float* b2  = (const float*)d_in[15];
    const float* Wf1 = (const float*)d_in[16];
    const float* bf1 = (const float*)d_in[17];
    const float* Wf2 = (const float*)d_in[18];
    const float* bf2 = (const float*)d_in[19];
    float* out = (float*)d_out;
    (void)in_sizes; (void)n_in; (void)out_size; (void)ws_size;

    const int* srcp = ei;
    const int* dstp = ei + N_EDGES;

    char* wsb = (char*)d_ws;
    size_t off = 0;
    auto alloc = [&](size_t bytes) -> char* {
        char* p = wsb + off;
        off = (off + bytes + 255) & ~(size_t)255;
        return p;
    };
    float* params = (float*)alloc(64);
    // region A: staged (25.6 MB), reused after k_scatter as hbuf (12.8) + obuf (12.8)
    char* regA = alloc((size_t)N_EDGES * 8 + 4096);
    int2*  staged = (int2*)regA;
    float* hbuf   = (float*)regA;
    float* obuf   = (float*)(regA + (size_t)N_NODES * HC * 4);
    int2*  epack  = (int2*)alloc((size_t)N_EDGES * 8);
    float* asrc   = (float*)alloc((size_t)N_NODES * 2 * 4);
    float* adst   = (float*)alloc((size_t)N_NODES * 2 * 4);
    int*   cnt    = (int*)alloc((size_t)NB2 * 4);
    int*   gstart = (int*)alloc((size_t)(NB2 + 1) * 4);
    int*   gcur   = (int*)alloc((size_t)NB2 * 4);
    int*   rowptr = (int*)alloc((size_t)(N_NODES + 1) * 4);

    hipMemsetAsync(params, 0, 64, stream);
    hipMemsetAsync(cnt, 0, (size_t)NB2 * 4, stream);

    const int nBlkB = (N_EDGES + EPB3 - 1) / EPB3;              // 98
    const int nBlkL = (N_NODES + 63) / 64;                      // 1563
    const int nBlkG = (N_NODES * 16 + 255) / 256;               // 6250

    // fused precompute + two-pass locality-aware counting sort
    k_pre<<<1024, 256, 0, stream>>>(ea, dstp, params, cnt);
    k_setup<<<1, 256, 0, stream>>>(We1, ae1, We2, ae2, params, cnt, gstart, gcur, rowptr);
    k_bucket<<<nBlkB, 256, 0, stream>>>(srcp, dstp, ea, gcur, staged);
    k_scatter<<<NB2, 256, 0, stream>>>(staged, gstart, rowptr, epack);

    // ----- layer 1 (hbuf/obuf overwrite staged region; stream-ordered, safe) -----
    k_linear<F_IN><<<nBlkL, 256, 0, stream>>>(x, W1, as1, ad1, hbuf, asrc, adst);
    k_gat<<<nBlkG, 256, 0, stream>>>(rowptr, epack, hbuf, asrc, adst, params, 2, b1, 1, obuf);

    // ----- layer 2 -----
    k_linear<HC><<<nBlkL, 256, 0, stream>>>(obuf, W2, as2, ad2, hbuf, asrc, adst);
    k_gat<<<nBlkG, 256, 0, stream>>>(rowptr, epack, hbuf, asrc, adst, params, 4, b2, 0, obuf);

    // ----- pool + MLP (fused; bounds via binary search on sorted batch) -----
    k_poolmlp<<<NGRAPH, 256, 0, stream>>>(obuf, batch, Wf1, bf1, Wf2, bf2, out);
}

// Round 8
// 483.177 us; speedup vs baseline: 1.1555x; 1.1555x over previous
//
#include <hip/hip_runtime.h>

#define N_NODES 100000
#define N_EDGES 3200000
#define F_IN    128
#define HC      32      // H*C
#define CH      16      // C per head
#define NGRAPH  64
#define NEG     0.2f

#define BSH   7                                   // 128 nodes per bucket
#define BNODE (1 << BSH)
#define NB2   ((N_NODES + BNODE - 1) >> BSH)      // 782 buckets
#define EPB2  8192                                // edges per k_bucket block

__device__ __forceinline__ float lrelu(float x) { return x > 0.f ? x : NEG * x; }

// ---------- fused: ea sum + bucket histogram (one edge stream) ----------

__global__ void k_pre(const float* __restrict__ ea, const int* __restrict__ dst,
                      float* __restrict__ params, int* __restrict__ cnt) {
    __shared__ int l[NB2];
    for (int i = threadIdx.x; i < NB2; i += 256) l[i] = 0;
    __syncthreads();
    float acc = 0.f;
    for (int e = blockIdx.x * blockDim.x + threadIdx.x; e < N_EDGES;
         e += gridDim.x * blockDim.x) {
        acc += ea[e];
        atomicAdd(&l[dst[e] >> BSH], 1);
    }
    for (int m = 32; m >= 1; m >>= 1) acc += __shfl_xor(acc, m, 64);
    __shared__ float sh[4];
    int lane = threadIdx.x & 63, wid = threadIdx.x >> 6;
    if (lane == 0) sh[wid] = acc;
    __syncthreads();
    if (threadIdx.x == 0)
        unsafeAtomicAdd(params, sh[0] + sh[1] + sh[2] + sh[3]);
    for (int i = threadIdx.x; i < NB2; i += 256)
        if (l[i]) atomicAdd(&cnt[i], l[i]);
}

// ---------- fused: params precompute + bucket scan (single block) ----------
// params: [0]=ea_sum, [1]=ea_mean, [2..3]=ce layer1, [4..5]=ce layer2

__global__ void k_setup(const float* __restrict__ We1, const float* __restrict__ ae1,
                        const float* __restrict__ We2, const float* __restrict__ ae2,
                        float* __restrict__ params, const int* __restrict__ cnt,
                        int* __restrict__ gstart, int* __restrict__ gcur,
                        int* __restrict__ rowptr) {
    int t = threadIdx.x;
    if (t < 2) {
        float c1 = 0.f, c2 = 0.f;
        for (int c = 0; c < CH; ++c) {
            c1 += We1[t * CH + c] * ae1[t * CH + c];
            c2 += We2[t * CH + c] * ae2[t * CH + c];
        }
        params[2 + t] = c1;
        params[4 + t] = c2;
        if (t == 0) params[1] = params[0] / (float)N_EDGES;
    }
    __shared__ int sh[256];
    int v[4];
    int s = 0;
    for (int j = 0; j < 4; ++j) {
        int i = t * 4 + j;
        v[j] = (i < NB2) ? cnt[i] : 0;
        s += v[j];
    }
    sh[t] = s;
    __syncthreads();
    for (int off = 1; off < 256; off <<= 1) {
        int u = (t >= off) ? sh[t - off] : 0;
        __syncthreads();
        sh[t] += u;
        __syncthreads();
    }
    int ex = sh[t] - s;   // exclusive prefix
    for (int j = 0; j < 4; ++j) {
        int i = t * 4 + j;
        if (i < NB2) { gstart[i] = ex; gcur[i] = ex; ex += v[j]; }
    }
    if (t == 255) {
        gstart[NB2] = N_EDGES;
        rowptr[N_NODES] = N_EDGES;
    }
}

// ---------- pass A: bucket scatter (8k edges/block, rank in registers) ----------

__global__ void k_bucket(const int* __restrict__ src, const int* __restrict__ dst,
                         const float* __restrict__ ea, int* __restrict__ gcur,
                         int2* __restrict__ staged) {
    __shared__ int lcur[NB2];
    __shared__ int gbase[NB2];
    int t = threadIdx.x;
    for (int i = t; i < NB2; i += 256) lcur[i] = 0;
    __syncthreads();
    int base = blockIdx.x * EPB2;
    int rank[EPB2 / 256];
#pragma unroll
    for (int i = 0; i < EPB2 / 256; ++i) {
        int e = base + i * 256 + t;
        if (e < N_EDGES) rank[i] = atomicAdd(&lcur[dst[e] >> BSH], 1);
    }
    __syncthreads();
    for (int i = t; i < NB2; i += 256)
        if (lcur[i] > 0) gbase[i] = atomicAdd(&gcur[i], lcur[i]);
    __syncthreads();
#pragma unroll
    for (int i = 0; i < EPB2 / 256; ++i) {
        int e = base + i * 256 + t;
        if (e < N_EDGES) {
            int dv = dst[e];
            staged[gbase[dv >> BSH] + rank[i]] =
                make_int2((src[e] << BSH) | (dv & (BNODE - 1)), __float_as_int(ea[e]));
        }
    }
}

// ---------- pass B: per-bucket local hist+scan, write rowptr + per-node-sorted epack ----------

__global__ void k_scatter(const int2* __restrict__ staged, const int* __restrict__ gstart,
                          int* __restrict__ rowptr, int2* __restrict__ epack) {
    __shared__ int cntl[BNODE];
    __shared__ int scanb[BNODE];
    __shared__ int cur[BNODE];
    int b = blockIdx.x, t = threadIdx.x;
    int nbase = b << BSH;
    int bcount = N_NODES - nbase;
    if (bcount > BNODE) bcount = BNODE;
    if (t < BNODE) cntl[t] = 0;
    __syncthreads();
    int st = gstart[b], en = gstart[b + 1];
    for (int e = st + t; e < en; e += 512)
        atomicAdd(&cntl[staged[e].x & (BNODE - 1)], 1);
    __syncthreads();
    if (t < BNODE) scanb[t] = cntl[t];
    __syncthreads();
    for (int off = 1; off < BNODE; off <<= 1) {
        int u = (t < BNODE && t >= off) ? scanb[t - off] : 0;
        __syncthreads();
        if (t < BNODE) scanb[t] += u;
        __syncthreads();
    }
    if (t < BNODE) {
        int ex = st + scanb[t] - cntl[t];   // exclusive, global
        cur[t] = ex;
        if (t < bcount) rowptr[nbase + t] = ex;
    }
    __syncthreads();
    for (int e = st + t; e < en; e += 512) {
        int2 r = staged[e];
        int pos = atomicAdd(&cur[r.x & (BNODE - 1)], 1);
        epack[pos] = r;
    }
}

// ---------- dense: h = x @ W (LDS-tiled), plus fused asrc/adst ----------

#define COLS(ac, xv)                                                     \
    ac[0] = fmaf(xv.x, w0.x, ac[0]); ac[1] = fmaf(xv.x, w0.y, ac[1]);    \
    ac[2] = fmaf(xv.x, w0.z, ac[2]); ac[3] = fmaf(xv.x, w0.w, ac[3]);    \
    ac[0] = fmaf(xv.y, w1.x, ac[0]); ac[1] = fmaf(xv.y, w1.y, ac[1]);    \
    ac[2] = fmaf(xv.y, w1.z, ac[2]); ac[3] = fmaf(xv.y, w1.w, ac[3]);    \
    ac[0] = fmaf(xv.z, w2.x, ac[0]); ac[1] = fmaf(xv.z, w2.y, ac[1]);    \
    ac[2] = fmaf(xv.z, w2.z, ac[2]); ac[3] = fmaf(xv.z, w2.w, ac[3]);    \
    ac[0] = fmaf(xv.w, w3.x, ac[0]); ac[1] = fmaf(xv.w, w3.y, ac[1]);    \
    ac[2] = fmaf(xv.w, w3.z, ac[2]); ac[3] = fmaf(xv.w, w3.w, ac[3]);

template <int FIN>
__global__ __launch_bounds__(256)
void k_linear(const float* __restrict__ x, const float* __restrict__ W,
              const float* __restrict__ a_src, const float* __restrict__ a_dst,
              float* __restrict__ h, float* __restrict__ asrc,
              float* __restrict__ adst) {
    constexpr int PAD = FIN + 4;
    __shared__ float ws[FIN * HC];
    __shared__ float xs[64 * PAD];
    int t = threadIdx.x;
    int nbase = blockIdx.x * 64;
    int bcount = N_NODES - nbase;
    if (bcount > 64) bcount = 64;

    for (int i = t; i < FIN * HC / 4; i += 256)
        ((float4*)ws)[i] = ((const float4*)W)[i];
    const float4* xg = (const float4*)(x + (size_t)nbase * FIN);
    int nf4 = bcount * FIN / 4;
    for (int i = t; i < 64 * FIN / 4; i += 256) {
        if (i < nf4) {
            float4 v = xg[i];
            int flat = i * 4;
            int row = flat / FIN, col = flat % FIN;
            *(float4*)&xs[row * PAD + col] = v;
        }
    }
    __syncthreads();

    int cg = t & 7, np = t >> 3;
    int n0 = np * 2, n1 = n0 + 1;
    float acc0[4] = {0.f, 0.f, 0.f, 0.f};
    float acc1[4] = {0.f, 0.f, 0.f, 0.f};
#pragma unroll
    for (int k = 0; k < FIN; k += 4) {
        float4 xa = *(const float4*)&xs[n0 * PAD + k];
        float4 xb = *(const float4*)&xs[n1 * PAD + k];
        const float4* wp = (const float4*)&ws[k * HC] + cg;
        float4 w0 = wp[0], w1 = wp[8], w2 = wp[16], w3 = wp[24];
        COLS(acc0, xa)
        COLS(acc1, xb)
    }

    int hh = cg >> 2;
    float s0 = 0.f, d0 = 0.f, s1 = 0.f, d1 = 0.f;
#pragma unroll
    for (int j = 0; j < 4; ++j) {
        float av = a_src[hh * CH + (cg & 3) * 4 + j];
        float dv = a_dst[hh * CH + (cg & 3) * 4 + j];
        s0 = fmaf(acc0[j], av, s0); d0 = fmaf(acc0[j], dv, d0);
        s1 = fmaf(acc1[j], av, s1); d1 = fmaf(acc1[j], dv, d1);
    }
    s0 += __shfl_xor(s0, 1, 64); s0 += __shfl_xor(s0, 2, 64);
    d0 += __shfl_xor(d0, 1, 64); d0 += __shfl_xor(d0, 2, 64);
    s1 += __shfl_xor(s1, 1, 64); s1 += __shfl_xor(s1, 2, 64);
    d1 += __shfl_xor(d1, 1, 64); d1 += __shfl_xor(d1, 2, 64);

    if (n0 < bcount) {
        *(float4*)&h[(size_t)(nbase + n0) * HC + cg * 4] =
            make_float4(acc0[0], acc0[1], acc0[2], acc0[3]);
        if ((cg & 3) == 0) {
            asrc[(nbase + n0) * 2 + hh] = s0;
            adst[(nbase + n0) * 2 + hh] = d0;
        }
    }
    if (n1 < bcount) {
        *(float4*)&h[(size_t)(nbase + n1) * HC + cg * 4] =
            make_float4(acc1[0], acc1[1], acc1[2], acc1[3]);
        if ((cg & 3) == 0) {
            asrc[(nbase + n1) * 2 + hh] = s1;
            adst[(nbase + n1) * 2 + hh] = d1;
        }
    }
}

// ---------- fused GAT layer: 16 lanes/node, float2 channels, 4x unrolled ----------

__global__ void k_gat(const int* __restrict__ rowptr, const int2* __restrict__ epack,
                      const float* __restrict__ h,
                      const float* __restrict__ asrc, const float* __restrict__ adst,
                      const float* __restrict__ params, int ceoff,
                      const float* __restrict__ bias, int do_relu,
                      float* __restrict__ out) {
    int tid = blockIdx.x * blockDim.x + threadIdx.x;
    int n = tid >> 4;
    if (n >= N_NODES) return;
    int c2 = tid & 15, hh = c2 >> 3;       // channels 2*c2, 2*c2+1; head = c2>>3
    int st = rowptr[n], en = rowptr[n + 1];
    float ce = params[ceoff + hh];
    float adn = adst[n * 2 + hh];
    const float2* h2 = (const float2*)h;
    float ax = 0.f, ay = 0.f, ssum = 0.f;
    int e = st;
    for (; e + 3 < en; e += 4) {
        int2 r0 = epack[e], r1 = epack[e + 1], r2 = epack[e + 2], r3 = epack[e + 3];
        int s0 = r0.x >> BSH, s1 = r1.x >> BSH, s2 = r2.x >> BSH, s3 = r3.x >> BSH;
        float a0 = asrc[s0 * 2 + hh], a1 = asrc[s1 * 2 + hh];
        float a2 = asrc[s2 * 2 + hh], a3 = asrc[s3 * 2 + hh];
        float2 h0 = h2[s0 * 16 + c2], h1 = h2[s1 * 16 + c2];
        float2 hx2 = h2[s2 * 16 + c2], h3 = h2[s3 * 16 + c2];
        float w0 = __expf(lrelu(a0 + adn + ce * __int_as_float(r0.y)));
        float w1 = __expf(lrelu(a1 + adn + ce * __int_as_float(r1.y)));
        float w2 = __expf(lrelu(a2 + adn + ce * __int_as_float(r2.y)));
        float w3 = __expf(lrelu(a3 + adn + ce * __int_as_float(r3.y)));
        ax = fmaf(w0, h0.x, ax); ay = fmaf(w0, h0.y, ay); ssum += w0;
        ax = fmaf(w1, h1.x, ax); ay = fmaf(w1, h1.y, ay); ssum += w1;
        ax = fmaf(w2, hx2.x, ax); ay = fmaf(w2, hx2.y, ay); ssum += w2;
        ax = fmaf(w3, h3.x, ax); ay = fmaf(w3, h3.y, ay); ssum += w3;
    }
    for (; e < en; ++e) {
        int2 r = epack[e];
        int sv = r.x >> BSH;
        float asv = asrc[sv * 2 + hh];
        float2 hv = h2[sv * 16 + c2];
        float wv = __expf(lrelu(asv + adn + ce * __int_as_float(r.y)));
        ax = fmaf(wv, hv.x, ax); ay = fmaf(wv, hv.y, ay);
        ssum += wv;
    }
    // self-loop (eattr = mean)
    float wself = __expf(lrelu(asrc[n * 2 + hh] + adn + ce * params[1]));
    float2 hs = h2[n * 16 + c2];
    ax = fmaf(wself, hs.x, ax); ay = fmaf(wself, hs.y, ay);
    ssum += wself;
    float inv = 1.f / (ssum + 1e-16f);
    float2 bv = ((const float2*)bias)[c2];
    float vx = ax * inv + bv.x, vy = ay * inv + bv.y;
    if (do_relu) { vx = fmaxf(vx, 0.f); vy = fmaxf(vy, 0.f); }
    ((float2*)out)[n * 16 + c2] = make_float2(vx, vy);
}

// ---------- fused pooling (binary search on sorted batch) + MLP head ----------

__global__ void k_poolmlp(const float* __restrict__ feat, const int* __restrict__ batch,
                          const float* __restrict__ Wf1, const float* __restrict__ bf1,
                          const float* __restrict__ Wf2, const float* __restrict__ bf2,
                          float* __restrict__ out) {
    int g = blockIdx.x;
    __shared__ int sse[2];
    if (threadIdx.x < 2) {
        int target = g + (int)threadIdx.x;
        int lo = 0, hi = N_NODES;
        while (lo < hi) {
            int mid = (lo + hi) >> 1;
            if (batch[mid] < target) lo = mid + 1; else hi = mid;
        }
        sse[threadIdx.x] = lo;
    }
    __syncthreads();
    int st = sse[0], en = sse[1];
    int c = threadIdx.x & 31, r = threadIdx.x >> 5;  // r in 0..7
    float acc = 0.f;
    for (int n = st + r; n < en; n += 8) acc += feat[(size_t)n * HC + c];
    __shared__ float sh[8][32];
    sh[r][c] = acc;
    __syncthreads();
    __shared__ float emb[32];
    __shared__ float hid[32];
    if (threadIdx.x < 32) {
        float t = 0.f;
        for (int r2 = 0; r2 < 8; ++r2) t += sh[r2][c];
        int cnt = en - st;
        emb[c] = t / (float)(cnt > 0 ? cnt : 1);
    }
    __syncthreads();
    if (threadIdx.x < 32) {
        int j = threadIdx.x;
        float a = bf1[j];
        for (int k = 0; k < 32; ++k) a = fmaf(emb[k], Wf1[k * 32 + j], a);
        hid[j] = fmaxf(a, 0.f);
    }
    __syncthreads();
    if (threadIdx.x < 2) {
        int j = threadIdx.x;
        float o = bf2[j];
        for (int k = 0; k < 32; ++k) o = fmaf(hid[k], Wf2[k * 2 + j], o);
        out[g * 2 + j] = o;
    }
}

extern "C" void kernel_launch(void* const* d_in, const int* in_sizes, int n_in,
                              void* d_out, int out_size, void* d_ws, size_t ws_size,
                              hipStream_t stream) {
    const float* x   = (const float*)d_in[0];
    const int*   ei  = (const int*)d_in[1];
    const float* ea  = (const float*)d_in[2];
    const int* batch = (const int*)d_in[3];
    const float* W1  = (const float*)d_in[4];
    const float* as1 = (const float*)d_in[5];
    const float* ad1 = (const float*)d_in[6];
    const float* We1 = (const float*)d_in[7];
    const float* ae1 = (const float*)d_in[8];
    const float* b1  = (const float*)d_in[9];
    const float* W2  = (const float*)d_in[10];
    const float* as2 = (const float*)d_in[11];
    const float* ad2 = (const float*)d_in[12];
    const float* We2 = (const float*)d_in[13];
    const float* ae2 = (const float*)d_in[14];
    const float* b2  = (const float*)d_in[15];
    const float* Wf1 = (const float*)d_in[16];
    const float* bf1 = (const float*)d_in[17];
    const float* Wf2 = (const float*)d_in[18];
    const float* bf2 = (const float*)d_in[19];
    float* out = (float*)d_out;
    (void)in_sizes; (void)n_in; (void)out_size; (void)ws_size;

    const int* srcp = ei;
    const int* dstp = ei + N_EDGES;

    char* wsb = (char*)d_ws;
    size_t off = 0;
    auto alloc = [&](size_t bytes) -> char* {
        char* p = wsb + off;
        off = (off + bytes + 255) & ~(size_t)255;
        return p;
    };
    float* params = (float*)alloc(64);
    // region A: staged (25.6 MB), reused after k_scatter as hbuf (12.8) + obuf (12.8)
    char* regA = alloc((size_t)N_EDGES * 8 + 4096);
    int2*  staged = (int2*)regA;
    float* hbuf   = (float*)regA;
    float* obuf   = (float*)(regA + (size_t)N_NODES * HC * 4);
    int2*  epack  = (int2*)alloc((size_t)N_EDGES * 8);
    float* asrc   = (float*)alloc((size_t)N_NODES * 2 * 4);
    float* adst   = (float*)alloc((size_t)N_NODES * 2 * 4);
    int*   cnt    = (int*)alloc((size_t)NB2 * 4);
    int*   gstart = (int*)alloc((size_t)(NB2 + 1) * 4);
    int*   gcur   = (int*)alloc((size_t)NB2 * 4);
    int*   rowptr = (int*)alloc((size_t)(N_NODES + 1) * 4);

    hipMemsetAsync(params, 0, 64, stream);
    hipMemsetAsync(cnt, 0, (size_t)NB2 * 4, stream);

    const int nBlkB = (N_EDGES + EPB2 - 1) / EPB2;              // 391
    const int nBlkL = (N_NODES + 63) / 64;                      // 1563
    const int nBlkG = (N_NODES * 16 + 255) / 256;               // 6250

    // fused precompute + two-pass locality-aware counting sort
    k_pre<<<1024, 256, 0, stream>>>(ea, dstp, params, cnt);
    k_setup<<<1, 256, 0, stream>>>(We1, ae1, We2, ae2, params, cnt, gstart, gcur, rowptr);
    k_bucket<<<nBlkB, 256, 0, stream>>>(srcp, dstp, ea, gcur, staged);
    k_scatter<<<NB2, 512, 0, stream>>>(staged, gstart, rowptr, epack);

    // ----- layer 1 (hbuf/obuf overwrite staged region; stream-ordered, safe) -----
    k_linear<F_IN><<<nBlkL, 256, 0, stream>>>(x, W1, as1, ad1, hbuf, asrc, adst);
    k_gat<<<nBlkG, 256, 0, stream>>>(rowptr, epack, hbuf, asrc, adst, params, 2, b1, 1, obuf);

    // ----- layer 2 -----
    k_linear<HC><<<nBlkL, 256, 0, stream>>>(obuf, W2, as2, ad2, hbuf, asrc, adst);
    k_gat<<<nBlkG, 256, 0, stream>>>(rowptr, epack, hbuf, asrc, adst, params, 4, b2, 0, obuf);

    // ----- pool + MLP (fused; bounds via binary search on sorted batch) -----
    k_poolmlp<<<NGRAPH, 256, 0, stream>>>(obuf, batch, Wf1, bf1, Wf2, bf2, out);
}

// Round 9
// 477.676 us; speedup vs baseline: 1.1688x; 1.0115x over previous
//
#include <hip/hip_runtime.h>

#define N_NODES 100000
#define N_EDGES 3200000
#define F_IN    128
#define HC      32      // H*C
#define CH      16      // C per head
#define NGRAPH  64
#define NEG     0.2f

#define BSH   7                                   // 128 nodes per bucket
#define BNODE (1 << BSH)
#define NB2   ((N_NODES + BNODE - 1) >> BSH)      // 782 buckets
#define EPB2  8192                                // edges per k_bucket block
#define BTHR  512                                 // k_bucket threads

__device__ __forceinline__ float lrelu(float x) { return x > 0.f ? x : NEG * x; }

// ---------- fused: ea sum + bucket histogram (one edge stream) ----------

__global__ void k_pre(const float* __restrict__ ea, const int* __restrict__ dst,
                      float* __restrict__ params, int* __restrict__ cnt) {
    __shared__ int l[NB2];
    for (int i = threadIdx.x; i < NB2; i += 256) l[i] = 0;
    __syncthreads();
    float acc = 0.f;
    for (int e = blockIdx.x * blockDim.x + threadIdx.x; e < N_EDGES;
         e += gridDim.x * blockDim.x) {
        acc += ea[e];
        atomicAdd(&l[dst[e] >> BSH], 1);
    }
    for (int m = 32; m >= 1; m >>= 1) acc += __shfl_xor(acc, m, 64);
    __shared__ float sh[4];
    int lane = threadIdx.x & 63, wid = threadIdx.x >> 6;
    if (lane == 0) sh[wid] = acc;
    __syncthreads();
    if (threadIdx.x == 0)
        unsafeAtomicAdd(params, sh[0] + sh[1] + sh[2] + sh[3]);
    for (int i = threadIdx.x; i < NB2; i += 256)
        if (l[i]) atomicAdd(&cnt[i], l[i]);
}

// ---------- fused: params precompute + bucket scan (single block) ----------
// params: [0]=ea_sum, [1]=ea_mean, [2..3]=ce layer1, [4..5]=ce layer2

__global__ void k_setup(const float* __restrict__ We1, const float* __restrict__ ae1,
                        const float* __restrict__ We2, const float* __restrict__ ae2,
                        float* __restrict__ params, const int* __restrict__ cnt,
                        int* __restrict__ gstart, int* __restrict__ gcur,
                        int* __restrict__ rowptr) {
    int t = threadIdx.x;
    if (t < 2) {
        float c1 = 0.f, c2 = 0.f;
        for (int c = 0; c < CH; ++c) {
            c1 += We1[t * CH + c] * ae1[t * CH + c];
            c2 += We2[t * CH + c] * ae2[t * CH + c];
        }
        params[2 + t] = c1;
        params[4 + t] = c2;
        if (t == 0) params[1] = params[0] / (float)N_EDGES;
    }
    __shared__ int sh[256];
    int v[4];
    int s = 0;
    for (int j = 0; j < 4; ++j) {
        int i = t * 4 + j;
        v[j] = (i < NB2) ? cnt[i] : 0;
        s += v[j];
    }
    sh[t] = s;
    __syncthreads();
    for (int off = 1; off < 256; off <<= 1) {
        int u = (t >= off) ? sh[t - off] : 0;
        __syncthreads();
        sh[t] += u;
        __syncthreads();
    }
    int ex = sh[t] - s;   // exclusive prefix
    for (int j = 0; j < 4; ++j) {
        int i = t * 4 + j;
        if (i < NB2) { gstart[i] = ex; gcur[i] = ex; ex += v[j]; }
    }
    if (t == 255) {
        gstart[NB2] = N_EDGES;
        rowptr[N_NODES] = N_EDGES;
    }
}

// ---------- pass A: bucket scatter (8k edges/block, 512 thr, rank in regs) ----------

__global__ void k_bucket(const int* __restrict__ src, const int* __restrict__ dst,
                         const float* __restrict__ ea, int* __restrict__ gcur,
                         int2* __restrict__ staged) {
    __shared__ int lcur[NB2];
    __shared__ int gbase[NB2];
    int t = threadIdx.x;
    for (int i = t; i < NB2; i += BTHR) lcur[i] = 0;
    __syncthreads();
    int base = blockIdx.x * EPB2;
    int rank[EPB2 / BTHR];
#pragma unroll
    for (int i = 0; i < EPB2 / BTHR; ++i) {
        int e = base + i * BTHR + t;
        if (e < N_EDGES) rank[i] = atomicAdd(&lcur[dst[e] >> BSH], 1);
    }
    __syncthreads();
    for (int i = t; i < NB2; i += BTHR)
        if (lcur[i] > 0) gbase[i] = atomicAdd(&gcur[i], lcur[i]);
    __syncthreads();
#pragma unroll
    for (int i = 0; i < EPB2 / BTHR; ++i) {
        int e = base + i * BTHR + t;
        if (e < N_EDGES) {
            int dv = dst[e];
            staged[gbase[dv >> BSH] + rank[i]] =
                make_int2((src[e] << BSH) | (dv & (BNODE - 1)), __float_as_int(ea[e]));
        }
    }
}

// ---------- pass B: per-bucket local hist+scan, write rowptr + per-node-sorted epack ----------

__global__ void k_scatter(const int2* __restrict__ staged, const int* __restrict__ gstart,
                          int* __restrict__ rowptr, int2* __restrict__ epack) {
    __shared__ int cntl[BNODE];
    __shared__ int scanb[BNODE];
    __shared__ int cur[BNODE];
    int b = blockIdx.x, t = threadIdx.x;
    int nbase = b << BSH;
    int bcount = N_NODES - nbase;
    if (bcount > BNODE) bcount = BNODE;
    if (t < BNODE) cntl[t] = 0;
    __syncthreads();
    int st = gstart[b], en = gstart[b + 1];
    for (int e = st + t; e < en; e += 512)
        atomicAdd(&cntl[staged[e].x & (BNODE - 1)], 1);
    __syncthreads();
    if (t < BNODE) scanb[t] = cntl[t];
    __syncthreads();
    for (int off = 1; off < BNODE; off <<= 1) {
        int u = (t < BNODE && t >= off) ? scanb[t - off] : 0;
        __syncthreads();
        if (t < BNODE) scanb[t] += u;
        __syncthreads();
    }
    if (t < BNODE) {
        int ex = st + scanb[t] - cntl[t];   // exclusive, global
        cur[t] = ex;
        if (t < bcount) rowptr[nbase + t] = ex;
    }
    __syncthreads();
    for (int e = st + t; e < en; e += 512) {
        int2 r = staged[e];
        int pos = atomicAdd(&cur[r.x & (BNODE - 1)], 1);
        epack[pos] = r;
    }
}

// ---------- dense: h = x @ W (LDS-tiled), plus fused asrc/adst ----------

#define COLS(ac, xv)                                                     \
    ac[0] = fmaf(xv.x, w0.x, ac[0]); ac[1] = fmaf(xv.x, w0.y, ac[1]);    \
    ac[2] = fmaf(xv.x, w0.z, ac[2]); ac[3] = fmaf(xv.x, w0.w, ac[3]);    \
    ac[0] = fmaf(xv.y, w1.x, ac[0]); ac[1] = fmaf(xv.y, w1.y, ac[1]);    \
    ac[2] = fmaf(xv.y, w1.z, ac[2]); ac[3] = fmaf(xv.y, w1.w, ac[3]);    \
    ac[0] = fmaf(xv.z, w2.x, ac[0]); ac[1] = fmaf(xv.z, w2.y, ac[1]);    \
    ac[2] = fmaf(xv.z, w2.z, ac[2]); ac[3] = fmaf(xv.z, w2.w, ac[3]);    \
    ac[0] = fmaf(xv.w, w3.x, ac[0]); ac[1] = fmaf(xv.w, w3.y, ac[1]);    \
    ac[2] = fmaf(xv.w, w3.z, ac[2]); ac[3] = fmaf(xv.w, w3.w, ac[3]);

template <int FIN>
__global__ __launch_bounds__(256)
void k_linear(const float* __restrict__ x, const float* __restrict__ W,
              const float* __restrict__ a_src, const float* __restrict__ a_dst,
              float* __restrict__ h, float* __restrict__ asrc,
              float* __restrict__ adst) {
    constexpr int PAD = FIN + 4;
    __shared__ float ws[FIN * HC];
    __shared__ float xs[64 * PAD];
    int t = threadIdx.x;
    int nbase = blockIdx.x * 64;
    int bcount = N_NODES - nbase;
    if (bcount > 64) bcount = 64;

    for (int i = t; i < FIN * HC / 4; i += 256)
        ((float4*)ws)[i] = ((const float4*)W)[i];
    const float4* xg = (const float4*)(x + (size_t)nbase * FIN);
    int nf4 = bcount * FIN / 4;
    for (int i = t; i < 64 * FIN / 4; i += 256) {
        if (i < nf4) {
            float4 v = xg[i];
            int flat = i * 4;
            int row = flat / FIN, col = flat % FIN;
            *(float4*)&xs[row * PAD + col] = v;
        }
    }
    __syncthreads();

    int cg = t & 7, np = t >> 3;
    int n0 = np * 2, n1 = n0 + 1;
    float acc0[4] = {0.f, 0.f, 0.f, 0.f};
    float acc1[4] = {0.f, 0.f, 0.f, 0.f};
#pragma unroll
    for (int k = 0; k < FIN; k += 4) {
        float4 xa = *(const float4*)&xs[n0 * PAD + k];
        float4 xb = *(const float4*)&xs[n1 * PAD + k];
        const float4* wp = (const float4*)&ws[k * HC] + cg;
        float4 w0 = wp[0], w1 = wp[8], w2 = wp[16], w3 = wp[24];
        COLS(acc0, xa)
        COLS(acc1, xb)
    }

    int hh = cg >> 2;
    float s0 = 0.f, d0 = 0.f, s1 = 0.f, d1 = 0.f;
#pragma unroll
    for (int j = 0; j < 4; ++j) {
        float av = a_src[hh * CH + (cg & 3) * 4 + j];
        float dv = a_dst[hh * CH + (cg & 3) * 4 + j];
        s0 = fmaf(acc0[j], av, s0); d0 = fmaf(acc0[j], dv, d0);
        s1 = fmaf(acc1[j], av, s1); d1 = fmaf(acc1[j], dv, d1);
    }
    s0 += __shfl_xor(s0, 1, 64); s0 += __shfl_xor(s0, 2, 64);
    d0 += __shfl_xor(d0, 1, 64); d0 += __shfl_xor(d0, 2, 64);
    s1 += __shfl_xor(s1, 1, 64); s1 += __shfl_xor(s1, 2, 64);
    d1 += __shfl_xor(d1, 1, 64); d1 += __shfl_xor(d1, 2, 64);

    if (n0 < bcount) {
        *(float4*)&h[(size_t)(nbase + n0) * HC + cg * 4] =
            make_float4(acc0[0], acc0[1], acc0[2], acc0[3]);
        if ((cg & 3) == 0) {
            asrc[(nbase + n0) * 2 + hh] = s0;
            adst[(nbase + n0) * 2 + hh] = d0;
        }
    }
    if (n1 < bcount) {
        *(float4*)&h[(size_t)(nbase + n1) * HC + cg * 4] =
            make_float4(acc1[0], acc1[1], acc1[2], acc1[3]);
        if ((cg & 3) == 0) {
            asrc[(nbase + n1) * 2 + hh] = s1;
            adst[(nbase + n1) * 2 + hh] = d1;
        }
    }
}

// ---------- fused GAT layer: 8 lanes/node, float4 channels, 4x unrolled ----------

__global__ void k_gat(const int* __restrict__ rowptr, const int2* __restrict__ epack,
                      const float* __restrict__ h,
                      const float* __restrict__ asrc, const float* __restrict__ adst,
                      const float* __restrict__ params, int ceoff,
                      const float* __restrict__ bias, int do_relu,
                      float* __restrict__ out) {
    int tid = blockIdx.x * blockDim.x + threadIdx.x;
    int n = tid >> 3;
    if (n >= N_NODES) return;
    int c4 = tid & 7, hh = c4 >> 2;       // channels 4*c4..4*c4+3; head = c4>>2
    int st = rowptr[n], en = rowptr[n + 1];
    float ce = params[ceoff + hh];
    float adn = adst[n * 2 + hh];
    const float4* h4 = (const float4*)h;
    float ax = 0.f, ay = 0.f, az = 0.f, aw = 0.f, ssum = 0.f;
    int e = st;
    for (; e + 3 < en; e += 4) {
        int2 r0 = epack[e], r1 = epack[e + 1], r2 = epack[e + 2], r3 = epack[e + 3];
        int s0 = r0.x >> BSH, s1 = r1.x >> BSH, s2 = r2.x >> BSH, s3 = r3.x >> BSH;
        float a0 = asrc[s0 * 2 + hh], a1 = asrc[s1 * 2 + hh];
        float a2 = asrc[s2 * 2 + hh], a3 = asrc[s3 * 2 + hh];
        float4 h0 = h4[s0 * 8 + c4], h1 = h4[s1 * 8 + c4];
        float4 hq2 = h4[s2 * 8 + c4], h3 = h4[s3 * 8 + c4];
        float w0 = __expf(lrelu(a0 + adn + ce * __int_as_float(r0.y)));
        float w1 = __expf(lrelu(a1 + adn + ce * __int_as_float(r1.y)));
        float w2 = __expf(lrelu(a2 + adn + ce * __int_as_float(r2.y)));
        float w3 = __expf(lrelu(a3 + adn + ce * __int_as_float(r3.y)));
        ax = fmaf(w0, h0.x, ax); ay = fmaf(w0, h0.y, ay);
        az = fmaf(w0, h0.z, az); aw = fmaf(w0, h0.w, aw); ssum += w0;
        ax = fmaf(w1, h1.x, ax); ay = fmaf(w1, h1.y, ay);
        az = fmaf(w1, h1.z, az); aw = fmaf(w1, h1.w, aw); ssum += w1;
        ax = fmaf(w2, hq2.x, ax); ay = fmaf(w2, hq2.y, ay);
        az = fmaf(w2, hq2.z, az); aw = fmaf(w2, hq2.w, aw); ssum += w2;
        ax = fmaf(w3, h3.x, ax); ay = fmaf(w3, h3.y, ay);
        az = fmaf(w3, h3.z, az); aw = fmaf(w3, h3.w, aw); ssum += w3;
    }
    for (; e < en; ++e) {
        int2 r = epack[e];
        int sv = r.x >> BSH;
        float asv = asrc[sv * 2 + hh];
        float4 hv = h4[sv * 8 + c4];
        float wv = __expf(lrelu(asv + adn + ce * __int_as_float(r.y)));
        ax = fmaf(wv, hv.x, ax); ay = fmaf(wv, hv.y, ay);
        az = fmaf(wv, hv.z, az); aw = fmaf(wv, hv.w, aw);
        ssum += wv;
    }
    // self-loop (eattr = mean)
    float wself = __expf(lrelu(asrc[n * 2 + hh] + adn + ce * params[1]));
    float4 hs = h4[n * 8 + c4];
    ax = fmaf(wself, hs.x, ax); ay = fmaf(wself, hs.y, ay);
    az = fmaf(wself, hs.z, az); aw = fmaf(wself, hs.w, aw);
    ssum += wself;
    float inv = 1.f / (ssum + 1e-16f);
    float4 bv = ((const float4*)bias)[c4];
    float vx = ax * inv + bv.x, vy = ay * inv + bv.y;
    float vz = az * inv + bv.z, vw = aw * inv + bv.w;
    if (do_relu) {
        vx = fmaxf(vx, 0.f); vy = fmaxf(vy, 0.f);
        vz = fmaxf(vz, 0.f); vw = fmaxf(vw, 0.f);
    }
    ((float4*)out)[n * 8 + c4] = make_float4(vx, vy, vz, vw);
}

// ---------- fused pooling (binary search on sorted batch) + MLP head ----------

__global__ void k_poolmlp(const float* __restrict__ feat, const int* __restrict__ batch,
                          const float* __restrict__ Wf1, const float* __restrict__ bf1,
                          const float* __restrict__ Wf2, const float* __restrict__ bf2,
                          float* __restrict__ out) {
    int g = blockIdx.x;
    __shared__ int sse[2];
    if (threadIdx.x < 2) {
        int target = g + (int)threadIdx.x;
        int lo = 0, hi = N_NODES;
        while (lo < hi) {
            int mid = (lo + hi) >> 1;
            if (batch[mid] < target) lo = mid + 1; else hi = mid;
        }
        sse[threadIdx.x] = lo;
    }
    __syncthreads();
    int st = sse[0], en = sse[1];
    int c = threadIdx.x & 31, r = threadIdx.x >> 5;  // r in 0..7
    float acc = 0.f;
    for (int n = st + r; n < en; n += 8) acc += feat[(size_t)n * HC + c];
    __shared__ float sh[8][32];
    sh[r][c] = acc;
    __syncthreads();
    __shared__ float emb[32];
    __shared__ float hid[32];
    if (threadIdx.x < 32) {
        float t = 0.f;
        for (int r2 = 0; r2 < 8; ++r2) t += sh[r2][c];
        int cnt = en - st;
        emb[c] = t / (float)(cnt > 0 ? cnt : 1);
    }
    __syncthreads();
    if (threadIdx.x < 32) {
        int j = threadIdx.x;
        float a = bf1[j];
        for (int k = 0; k < 32; ++k) a = fmaf(emb[k], Wf1[k * 32 + j], a);
        hid[j] = fmaxf(a, 0.f);
    }
    __syncthreads();
    if (threadIdx.x < 2) {
        int j = threadIdx.x;
        float o = bf2[j];
        for (int k = 0; k < 32; ++k) o = fmaf(hid[k], Wf2[k * 2 + j], o);
        out[g * 2 + j] = o;
    }
}

extern "C" void kernel_launch(void* const* d_in, const int* in_sizes, int n_in,
                              void* d_out, int out_size, void* d_ws, size_t ws_size,
                              hipStream_t stream) {
    const float* x   = (const float*)d_in[0];
    const int*   ei  = (const int*)d_in[1];
    const float* ea  = (const float*)d_in[2];
    const int* batch = (const int*)d_in[3];
    const float* W1  = (const float*)d_in[4];
    const float* as1 = (const float*)d_in[5];
    const float* ad1 = (const float*)d_in[6];
    const float* We1 = (const float*)d_in[7];
    const float* ae1 = (const float*)d_in[8];
    const float* b1  = (const float*)d_in[9];
    const float* W2  = (const float*)d_in[10];
    const float* as2 = (const float*)d_in[11];
    const float* ad2 = (const float*)d_in[12];
    const float* We2 = (const float*)d_in[13];
    const float* ae2 = (const float*)d_in[14];
    const float* b2  = (const float*)d_in[15];
    const float* Wf1 = (const float*)d_in[16];
    const float* bf1 = (const float*)d_in[17];
    const float* Wf2 = (const float*)d_in[18];
    const float* bf2 = (const float*)d_in[19];
    float* out = (float*)d_out;
    (void)in_sizes; (void)n_in; (void)out_size; (void)ws_size;

    const int* srcp = ei;
    const int* dstp = ei + N_EDGES;

    char* wsb = (char*)d_ws;
    size_t off = 0;
    auto alloc = [&](size_t bytes) -> char* {
        char* p = wsb + off;
        off = (off + bytes + 255) & ~(size_t)255;
        return p;
    };
    float* params = (float*)alloc(64);
    // region A: staged (25.6 MB), reused after k_scatter as hbuf (12.8) + obuf (12.8)
    char* regA = alloc((size_t)N_EDGES * 8 + 4096);
    int2*  staged = (int2*)regA;
    float* hbuf   = (float*)regA;
    float* obuf   = (float*)(regA + (size_t)N_NODES * HC * 4);
    int2*  epack  = (int2*)alloc((size_t)N_EDGES * 8);
    float* asrc   = (float*)alloc((size_t)N_NODES * 2 * 4);
    float* adst   = (float*)alloc((size_t)N_NODES * 2 * 4);
    int*   cnt    = (int*)alloc((size_t)NB2 * 4);
    int*   gstart = (int*)alloc((size_t)(NB2 + 1) * 4);
    int*   gcur   = (int*)alloc((size_t)NB2 * 4);
    int*   rowptr = (int*)alloc((size_t)(N_NODES + 1) * 4);

    hipMemsetAsync(params, 0, 64, stream);
    hipMemsetAsync(cnt, 0, (size_t)NB2 * 4, stream);

    const int nBlkB = (N_EDGES + EPB2 - 1) / EPB2;              // 391
    const int nBlkL = (N_NODES + 63) / 64;                      // 1563
    const int nBlkG = (N_NODES * 8 + 255) / 256;                // 3125

    // fused precompute + two-pass locality-aware counting sort
    k_pre<<<1024, 256, 0, stream>>>(ea, dstp, params, cnt);
    k_setup<<<1, 256, 0, stream>>>(We1, ae1, We2, ae2, params, cnt, gstart, gcur, rowptr);
    k_bucket<<<nBlkB, BTHR, 0, stream>>>(srcp, dstp, ea, gcur, staged);
    k_scatter<<<NB2, 512, 0, stream>>>(staged, gstart, rowptr, epack);

    // ----- layer 1 (hbuf/obuf overwrite staged region; stream-ordered, safe) -----
    k_linear<F_IN><<<nBlkL, 256, 0, stream>>>(x, W1, as1, ad1, hbuf, asrc, adst);
    k_gat<<<nBlkG, 256, 0, stream>>>(rowptr, epack, hbuf, asrc, adst, params, 2, b1, 1, obuf);

    // ----- layer 2 -----
    k_linear<HC><<<nBlkL, 256, 0, stream>>>(obuf, W2, as2, ad2, hbuf, asrc, adst);
    k_gat<<<nBlkG, 256, 0, stream>>>(rowptr, epack, hbuf, asrc, adst, params, 4, b2, 0, obuf);

    // ----- pool + MLP (fused; bounds via binary search on sorted batch) -----
    k_poolmlp<<<NGRAPH, 256, 0, stream>>>(obuf, batch, Wf1, bf1, Wf2, bf2, out);
}

// Round 10
// 471.277 us; speedup vs baseline: 1.1847x; 1.0136x over previous
//
#include <hip/hip_runtime.h>

#define N_NODES 100000
#define N_EDGES 3200000
#define F_IN    128
#define HC      32      // H*C
#define CH      16      // C per head
#define NGRAPH  64
#define NEG     0.2f

#define BSH   8                                   // 256 nodes per bucket
#define BNODE (1 << BSH)
#define NB2   ((N_NODES + BNODE - 1) >> BSH)      // 391 buckets
#define EPB2  8192                                // edges per k_bucket block
#define BTHR  1024                                // k_bucket threads

__device__ __forceinline__ float lrelu(float x) { return x > 0.f ? x : NEG * x; }

// ---------- fused: ea sum + bucket histogram (one edge stream) ----------

__global__ void k_pre(const float* __restrict__ ea, const int* __restrict__ dst,
                      float* __restrict__ params, int* __restrict__ cnt) {
    __shared__ int l[NB2];
    for (int i = threadIdx.x; i < NB2; i += 256) l[i] = 0;
    __syncthreads();
    float acc = 0.f;
    for (int e = blockIdx.x * blockDim.x + threadIdx.x; e < N_EDGES;
         e += gridDim.x * blockDim.x) {
        acc += ea[e];
        atomicAdd(&l[dst[e] >> BSH], 1);
    }
    for (int m = 32; m >= 1; m >>= 1) acc += __shfl_xor(acc, m, 64);
    __shared__ float sh[4];
    int lane = threadIdx.x & 63, wid = threadIdx.x >> 6;
    if (lane == 0) sh[wid] = acc;
    __syncthreads();
    if (threadIdx.x == 0)
        unsafeAtomicAdd(params, sh[0] + sh[1] + sh[2] + sh[3]);
    for (int i = threadIdx.x; i < NB2; i += 256)
        if (l[i]) atomicAdd(&cnt[i], l[i]);
}

// ---------- fused: params precompute + bucket scan (single block) ----------
// params: [0]=ea_sum, [1]=ea_mean, [2..3]=ce layer1, [4..5]=ce layer2

__global__ void k_setup(const float* __restrict__ We1, const float* __restrict__ ae1,
                        const float* __restrict__ We2, const float* __restrict__ ae2,
                        float* __restrict__ params, const int* __restrict__ cnt,
                        int* __restrict__ gstart, int* __restrict__ gcur,
                        int* __restrict__ rowptr) {
    int t = threadIdx.x;
    if (t < 2) {
        float c1 = 0.f, c2 = 0.f;
        for (int c = 0; c < CH; ++c) {
            c1 += We1[t * CH + c] * ae1[t * CH + c];
            c2 += We2[t * CH + c] * ae2[t * CH + c];
        }
        params[2 + t] = c1;
        params[4 + t] = c2;
        if (t == 0) params[1] = params[0] / (float)N_EDGES;
    }
    __shared__ int sh[256];
    int v[4];
    int s = 0;
    for (int j = 0; j < 4; ++j) {
        int i = t * 4 + j;
        v[j] = (i < NB2) ? cnt[i] : 0;
        s += v[j];
    }
    sh[t] = s;
    __syncthreads();
    for (int off = 1; off < 256; off <<= 1) {
        int u = (t >= off) ? sh[t - off] : 0;
        __syncthreads();
        sh[t] += u;
        __syncthreads();
    }
    int ex = sh[t] - s;   // exclusive prefix
    for (int j = 0; j < 4; ++j) {
        int i = t * 4 + j;
        if (i < NB2) { gstart[i] = ex; gcur[i] = ex; ex += v[j]; }
    }
    if (t == 255) {
        gstart[NB2] = N_EDGES;
        rowptr[N_NODES] = N_EDGES;
    }
}

// ---------- pass A: bucket scatter (8k edges/block, 1024 thr, rank in regs) ----------

__global__ void k_bucket(const int* __restrict__ src, const int* __restrict__ dst,
                         const float* __restrict__ ea, int* __restrict__ gcur,
                         int2* __restrict__ staged) {
    __shared__ int lcur[NB2];
    __shared__ int gbase[NB2];
    int t = threadIdx.x;
    for (int i = t; i < NB2; i += BTHR) lcur[i] = 0;
    __syncthreads();
    int base = blockIdx.x * EPB2;
    int rank[EPB2 / BTHR];
#pragma unroll
    for (int i = 0; i < EPB2 / BTHR; ++i) {
        int e = base + i * BTHR + t;
        if (e < N_EDGES) rank[i] = atomicAdd(&lcur[dst[e] >> BSH], 1);
    }
    __syncthreads();
    for (int i = t; i < NB2; i += BTHR)
        if (lcur[i] > 0) gbase[i] = atomicAdd(&gcur[i], lcur[i]);
    __syncthreads();
#pragma unroll
    for (int i = 0; i < EPB2 / BTHR; ++i) {
        int e = base + i * BTHR + t;
        if (e < N_EDGES) {
            int dv = dst[e];
            staged[gbase[dv >> BSH] + rank[i]] =
                make_int2((src[e] << BSH) | (dv & (BNODE - 1)), __float_as_int(ea[e]));
        }
    }
}

// ---------- pass B: per-bucket local hist+scan, write rowptr + per-node-sorted epack ----------

__global__ void k_scatter(const int2* __restrict__ staged, const int* __restrict__ gstart,
                          int* __restrict__ rowptr, int2* __restrict__ epack) {
    __shared__ int cntl[BNODE];
    __shared__ int scanb[BNODE];
    __shared__ int cur[BNODE];
    int b = blockIdx.x, t = threadIdx.x;
    int nbase = b << BSH;
    int bcount = N_NODES - nbase;
    if (bcount > BNODE) bcount = BNODE;
    if (t < BNODE) cntl[t] = 0;
    __syncthreads();
    int st = gstart[b], en = gstart[b + 1];
    for (int e = st + t; e < en; e += 1024)
        atomicAdd(&cntl[staged[e].x & (BNODE - 1)], 1);
    __syncthreads();
    if (t < BNODE) scanb[t] = cntl[t];
    __syncthreads();
    for (int off = 1; off < BNODE; off <<= 1) {
        int u = (t < BNODE && t >= off) ? scanb[t - off] : 0;
        __syncthreads();
        if (t < BNODE) scanb[t] += u;
        __syncthreads();
    }
    if (t < BNODE) {
        int ex = st + scanb[t] - cntl[t];   // exclusive, global
        cur[t] = ex;
        if (t < bcount) rowptr[nbase + t] = ex;
    }
    __syncthreads();
    for (int e = st + t; e < en; e += 1024) {
        int2 r = staged[e];
        int pos = atomicAdd(&cur[r.x & (BNODE - 1)], 1);
        epack[pos] = r;
    }
}

// ---------- dense: h = x @ W (LDS-tiled), plus fused asrc/adst ----------

#define COLS(ac, xv)                                                     \
    ac[0] = fmaf(xv.x, w0.x, ac[0]); ac[1] = fmaf(xv.x, w0.y, ac[1]);    \
    ac[2] = fmaf(xv.x, w0.z, ac[2]); ac[3] = fmaf(xv.x, w0.w, ac[3]);    \
    ac[0] = fmaf(xv.y, w1.x, ac[0]); ac[1] = fmaf(xv.y, w1.y, ac[1]);    \
    ac[2] = fmaf(xv.y, w1.z, ac[2]); ac[3] = fmaf(xv.y, w1.w, ac[3]);    \
    ac[0] = fmaf(xv.z, w2.x, ac[0]); ac[1] = fmaf(xv.z, w2.y, ac[1]);    \
    ac[2] = fmaf(xv.z, w2.z, ac[2]); ac[3] = fmaf(xv.z, w2.w, ac[3]);    \
    ac[0] = fmaf(xv.w, w3.x, ac[0]); ac[1] = fmaf(xv.w, w3.y, ac[1]);    \
    ac[2] = fmaf(xv.w, w3.z, ac[2]); ac[3] = fmaf(xv.w, w3.w, ac[3]);

template <int FIN>
__global__ __launch_bounds__(256)
void k_linear(const float* __restrict__ x, const float* __restrict__ W,
              const float* __restrict__ a_src, const float* __restrict__ a_dst,
              float* __restrict__ h, float* __restrict__ asrc,
              float* __restrict__ adst) {
    constexpr int PAD = FIN + 4;
    __shared__ float ws[FIN * HC];
    __shared__ float xs[64 * PAD];
    int t = threadIdx.x;
    int nbase = blockIdx.x * 64;
    int bcount = N_NODES - nbase;
    if (bcount > 64) bcount = 64;

    for (int i = t; i < FIN * HC / 4; i += 256)
        ((float4*)ws)[i] = ((const float4*)W)[i];
    const float4* xg = (const float4*)(x + (size_t)nbase * FIN);
    int nf4 = bcount * FIN / 4;
    for (int i = t; i < 64 * FIN / 4; i += 256) {
        if (i < nf4) {
            float4 v = xg[i];
            int flat = i * 4;
            int row = flat / FIN, col = flat % FIN;
            *(float4*)&xs[row * PAD + col] = v;
        }
    }
    __syncthreads();

    int cg = t & 7, np = t >> 3;
    int n0 = np * 2, n1 = n0 + 1;
    float acc0[4] = {0.f, 0.f, 0.f, 0.f};
    float acc1[4] = {0.f, 0.f, 0.f, 0.f};
#pragma unroll
    for (int k = 0; k < FIN; k += 4) {
        float4 xa = *(const float4*)&xs[n0 * PAD + k];
        float4 xb = *(const float4*)&xs[n1 * PAD + k];
        const float4* wp = (const float4*)&ws[k * HC] + cg;
        float4 w0 = wp[0], w1 = wp[8], w2 = wp[16], w3 = wp[24];
        COLS(acc0, xa)
        COLS(acc1, xb)
    }

    int hh = cg >> 2;
    float s0 = 0.f, d0 = 0.f, s1 = 0.f, d1 = 0.f;
#pragma unroll
    for (int j = 0; j < 4; ++j) {
        float av = a_src[hh * CH + (cg & 3) * 4 + j];
        float dv = a_dst[hh * CH + (cg & 3) * 4 + j];
        s0 = fmaf(acc0[j], av, s0); d0 = fmaf(acc0[j], dv, d0);
        s1 = fmaf(acc1[j], av, s1); d1 = fmaf(acc1[j], dv, d1);
    }
    s0 += __shfl_xor(s0, 1, 64); s0 += __shfl_xor(s0, 2, 64);
    d0 += __shfl_xor(d0, 1, 64); d0 += __shfl_xor(d0, 2, 64);
    s1 += __shfl_xor(s1, 1, 64); s1 += __shfl_xor(s1, 2, 64);
    d1 += __shfl_xor(d1, 1, 64); d1 += __shfl_xor(d1, 2, 64);

    if (n0 < bcount) {
        *(float4*)&h[(size_t)(nbase + n0) * HC + cg * 4] =
            make_float4(acc0[0], acc0[1], acc0[2], acc0[3]);
        if ((cg & 3) == 0) {
            asrc[(nbase + n0) * 2 + hh] = s0;
            adst[(nbase + n0) * 2 + hh] = d0;
        }
    }
    if (n1 < bcount) {
        *(float4*)&h[(size_t)(nbase + n1) * HC + cg * 4] =
            make_float4(acc1[0], acc1[1], acc1[2], acc1[3]);
        if ((cg & 3) == 0) {
            asrc[(nbase + n1) * 2 + hh] = s1;
            adst[(nbase + n1) * 2 + hh] = d1;
        }
    }
}

// ---------- fused GAT layer: 8 lanes/node, float4 channels, 4x unrolled ----------

__global__ void k_gat(const int* __restrict__ rowptr, const int2* __restrict__ epack,
                      const float* __restrict__ h,
                      const float* __restrict__ asrc, const float* __restrict__ adst,
                      const float* __restrict__ params, int ceoff,
                      const float* __restrict__ bias, int do_relu,
                      float* __restrict__ out) {
    int tid = blockIdx.x * blockDim.x + threadIdx.x;
    int n = tid >> 3;
    if (n >= N_NODES) return;
    int c4 = tid & 7, hh = c4 >> 2;       // channels 4*c4..4*c4+3; head = c4>>2
    int st = rowptr[n], en = rowptr[n + 1];
    float ce = params[ceoff + hh];
    float adn = adst[n * 2 + hh];
    const float4* h4 = (const float4*)h;
    float ax = 0.f, ay = 0.f, az = 0.f, aw = 0.f, ssum = 0.f;
    int e = st;
    for (; e + 3 < en; e += 4) {
        int2 r0 = epack[e], r1 = epack[e + 1], r2 = epack[e + 2], r3 = epack[e + 3];
        int s0 = r0.x >> BSH, s1 = r1.x >> BSH, s2 = r2.x >> BSH, s3 = r3.x >> BSH;
        float a0 = asrc[s0 * 2 + hh], a1 = asrc[s1 * 2 + hh];
        float a2 = asrc[s2 * 2 + hh], a3 = asrc[s3 * 2 + hh];
        float4 h0 = h4[s0 * 8 + c4], h1 = h4[s1 * 8 + c4];
        float4 hq2 = h4[s2 * 8 + c4], h3 = h4[s3 * 8 + c4];
        float w0 = __expf(lrelu(a0 + adn + ce * __int_as_float(r0.y)));
        float w1 = __expf(lrelu(a1 + adn + ce * __int_as_float(r1.y)));
        float w2 = __expf(lrelu(a2 + adn + ce * __int_as_float(r2.y)));
        float w3 = __expf(lrelu(a3 + adn + ce * __int_as_float(r3.y)));
        ax = fmaf(w0, h0.x, ax); ay = fmaf(w0, h0.y, ay);
        az = fmaf(w0, h0.z, az); aw = fmaf(w0, h0.w, aw); ssum += w0;
        ax = fmaf(w1, h1.x, ax); ay = fmaf(w1, h1.y, ay);
        az = fmaf(w1, h1.z, az); aw = fmaf(w1, h1.w, aw); ssum += w1;
        ax = fmaf(w2, hq2.x, ax); ay = fmaf(w2, hq2.y, ay);
        az = fmaf(w2, hq2.z, az); aw = fmaf(w2, hq2.w, aw); ssum += w2;
        ax = fmaf(w3, h3.x, ax); ay = fmaf(w3, h3.y, ay);
        az = fmaf(w3, h3.z, az); aw = fmaf(w3, h3.w, aw); ssum += w3;
    }
    for (; e < en; ++e) {
        int2 r = epack[e];
        int sv = r.x >> BSH;
        float asv = asrc[sv * 2 + hh];
        float4 hv = h4[sv * 8 + c4];
        float wv = __expf(lrelu(asv + adn + ce * __int_as_float(r.y)));
        ax = fmaf(wv, hv.x, ax); ay = fmaf(wv, hv.y, ay);
        az = fmaf(wv, hv.z, az); aw = fmaf(wv, hv.w, aw);
        ssum += wv;
    }
    // self-loop (eattr = mean)
    float wself = __expf(lrelu(asrc[n * 2 + hh] + adn + ce * params[1]));
    float4 hs = h4[n * 8 + c4];
    ax = fmaf(wself, hs.x, ax); ay = fmaf(wself, hs.y, ay);
    az = fmaf(wself, hs.z, az); aw = fmaf(wself, hs.w, aw);
    ssum += wself;
    float inv = 1.f / (ssum + 1e-16f);
    float4 bv = ((const float4*)bias)[c4];
    float vx = ax * inv + bv.x, vy = ay * inv + bv.y;
    float vz = az * inv + bv.z, vw = aw * inv + bv.w;
    if (do_relu) {
        vx = fmaxf(vx, 0.f); vy = fmaxf(vy, 0.f);
        vz = fmaxf(vz, 0.f); vw = fmaxf(vw, 0.f);
    }
    ((float4*)out)[n * 8 + c4] = make_float4(vx, vy, vz, vw);
}

// ---------- fused pooling (binary search on sorted batch) + MLP head ----------

__global__ void k_poolmlp(const float* __restrict__ feat, const int* __restrict__ batch,
                          const float* __restrict__ Wf1, const float* __restrict__ bf1,
                          const float* __restrict__ Wf2, const float* __restrict__ bf2,
                          float* __restrict__ out) {
    int g = blockIdx.x;
    __shared__ int sse[2];
    if (threadIdx.x < 2) {
        int target = g + (int)threadIdx.x;
        int lo = 0, hi = N_NODES;
        while (lo < hi) {
            int mid = (lo + hi) >> 1;
            if (batch[mid] < target) lo = mid + 1; else hi = mid;
        }
        sse[threadIdx.x] = lo;
    }
    __syncthreads();
    int st = sse[0], en = sse[1];
    int c = threadIdx.x & 31, r = threadIdx.x >> 5;  // r in 0..7
    float acc = 0.f;
    for (int n = st + r; n < en; n += 8) acc += feat[(size_t)n * HC + c];
    __shared__ float sh[8][32];
    sh[r][c] = acc;
    __syncthreads();
    __shared__ float emb[32];
    __shared__ float hid[32];
    if (threadIdx.x < 32) {
        float t = 0.f;
        for (int r2 = 0; r2 < 8; ++r2) t += sh[r2][c];
        int cnt = en - st;
        emb[c] = t / (float)(cnt > 0 ? cnt : 1);
    }
    __syncthreads();
    if (threadIdx.x < 32) {
        int j = threadIdx.x;
        float a = bf1[j];
        for (int k = 0; k < 32; ++k) a = fmaf(emb[k], Wf1[k * 32 + j], a);
        hid[j] = fmaxf(a, 0.f);
    }
    __syncthreads();
    if (threadIdx.x < 2) {
        int j = threadIdx.x;
        float o = bf2[j];
        for (int k = 0; k < 32; ++k) o = fmaf(hid[k], Wf2[k * 2 + j], o);
        out[g * 2 + j] = o;
    }
}

extern "C" void kernel_launch(void* const* d_in, const int* in_sizes, int n_in,
                              void* d_out, int out_size, void* d_ws, size_t ws_size,
                              hipStream_t stream) {
    const float* x   = (const float*)d_in[0];
    const int*   ei  = (const int*)d_in[1];
    const float* ea  = (const float*)d_in[2];
    const int* batch = (const int*)d_in[3];
    const float* W1  = (const float*)d_in[4];
    const float* as1 = (const float*)d_in[5];
    const float* ad1 = (const float*)d_in[6];
    const float* We1 = (const float*)d_in[7];
    const float* ae1 = (const float*)d_in[8];
    const float* b1  = (const float*)d_in[9];
    const float* W2  = (const float*)d_in[10];
    const float* as2 = (const float*)d_in[11];
    const float* ad2 = (const float*)d_in[12];
    const float* We2 = (const float*)d_in[13];
    const float* ae2 = (const float*)d_in[14];
    const float* b2  = (const float*)d_in[15];
    const float* Wf1 = (const float*)d_in[16];
    const float* bf1 = (const float*)d_in[17];
    const float* Wf2 = (const float*)d_in[18];
    const float* bf2 = (const float*)d_in[19];
    float* out = (float*)d_out;
    (void)in_sizes; (void)n_in; (void)out_size; (void)ws_size;

    const int* srcp = ei;
    const int* dstp = ei + N_EDGES;

    char* wsb = (char*)d_ws;
    size_t off = 0;
    auto alloc = [&](size_t bytes) -> char* {
        char* p = wsb + off;
        off = (off + bytes + 255) & ~(size_t)255;
        return p;
    };
    float* params = (float*)alloc(64);
    // region A: staged (25.6 MB), reused after k_scatter as hbuf (12.8) + obuf (12.8)
    char* regA = alloc((size_t)N_EDGES * 8 + 4096);
    int2*  staged = (int2*)regA;
    float* hbuf   = (float*)regA;
    float* obuf   = (float*)(regA + (size_t)N_NODES * HC * 4);
    int2*  epack  = (int2*)alloc((size_t)N_EDGES * 8);
    float* asrc   = (float*)alloc((size_t)N_NODES * 2 * 4);
    float* adst   = (float*)alloc((size_t)N_NODES * 2 * 4);
    int*   cnt    = (int*)alloc((size_t)NB2 * 4);
    int*   gstart = (int*)alloc((size_t)(NB2 + 1) * 4);
    int*   gcur   = (int*)alloc((size_t)NB2 * 4);
    int*   rowptr = (int*)alloc((size_t)(N_NODES + 1) * 4);

    hipMemsetAsync(params, 0, 64, stream);
    hipMemsetAsync(cnt, 0, (size_t)NB2 * 4, stream);

    const int nBlkB = (N_EDGES + EPB2 - 1) / EPB2;              // 391
    const int nBlkL = (N_NODES + 63) / 64;                      // 1563
    const int nBlkG = (N_NODES * 8 + 255) / 256;                // 3125

    // fused precompute + two-pass locality-aware counting sort
    k_pre<<<1024, 256, 0, stream>>>(ea, dstp, params, cnt);
    k_setup<<<1, 256, 0, stream>>>(We1, ae1, We2, ae2, params, cnt, gstart, gcur, rowptr);
    k_bucket<<<nBlkB, BTHR, 0, stream>>>(srcp, dstp, ea, gcur, staged);
    k_scatter<<<NB2, 1024, 0, stream>>>(staged, gstart, rowptr, epack);

    // ----- layer 1 (hbuf/obuf overwrite staged region; stream-ordered, safe) -----
    k_linear<F_IN><<<nBlkL, 256, 0, stream>>>(x, W1, as1, ad1, hbuf, asrc, adst);
    k_gat<<<nBlkG, 256, 0, stream>>>(rowptr, epack, hbuf, asrc, adst, params, 2, b1, 1, obuf);

    // ----- layer 2 -----
    k_linear<HC><<<nBlkL, 256, 0, stream>>>(obuf, W2, as2, ad2, hbuf, asrc, adst);
    k_gat<<<nBlkG, 256, 0, stream>>>(rowptr, epack, hbuf, asrc, adst, params, 4, b2, 0, obuf);

    // ----- pool + MLP (fused; bounds via binary search on sorted batch) -----
    k_poolmlp<<<NGRAPH, 256, 0, stream>>>(obuf, batch, Wf1, bf1, Wf2, bf2, out);
}

// Round 12
// 450.743 us; speedup vs baseline: 1.2387x; 1.0456x over previous
//
#include <hip/hip_runtime.h>

#define N_NODES 100000
#define N_EDGES 3200000
#define F_IN    128
#define HC      32      // H*C
#define CH      16      // C per head
#define NGRAPH  64
#define NEG     0.2f

#define BSH   8                                   // 256 nodes per bucket
#define BNODE (1 << BSH)
#define NB2   ((N_NODES + BNODE - 1) >> BSH)      // 391 buckets
#define CAP   9216                                // fixed staged slot per bucket (mean 8184 + 11 sigma)
#define EPB2  8192                                // edges per k_bucket block
#define BTHR  1024                                // k_bucket threads

__device__ __forceinline__ float lrelu(float x) { return x > 0.f ? x : NEG * x; }

// ---------- init: fixed bucket bases + params zero ----------

__global__ void k_init(int* __restrict__ gcur, float* __restrict__ params) {
    int t = threadIdx.x;
    if (t < NB2) gcur[t] = t * CAP;
    if (t < 16) params[t] = 0.f;
}

// ---------- pass A: bucket scatter into fixed-capacity slots + fused ea-sum ----------

__global__ void k_bucket(const int* __restrict__ src, const int* __restrict__ dst,
                         const float* __restrict__ ea, int* __restrict__ gcur,
                         int2* __restrict__ staged, float* __restrict__ params) {
    __shared__ int lcur[NB2];
    __shared__ int gbase[NB2];
    int t = threadIdx.x;
    for (int i = t; i < NB2; i += BTHR) lcur[i] = 0;
    __syncthreads();
    int base = blockIdx.x * EPB2;
    int rank[EPB2 / BTHR];
#pragma unroll
    for (int i = 0; i < EPB2 / BTHR; ++i) {
        int e = base + i * BTHR + t;
        if (e < N_EDGES) rank[i] = atomicAdd(&lcur[dst[e] >> BSH], 1);
    }
    __syncthreads();
    for (int i = t; i < NB2; i += BTHR)
        if (lcur[i] > 0) gbase[i] = atomicAdd(&gcur[i], lcur[i]);
    __syncthreads();
    float acc = 0.f;
#pragma unroll
    for (int i = 0; i < EPB2 / BTHR; ++i) {
        int e = base + i * BTHR + t;
        if (e < N_EDGES) {
            int dv = dst[e];
            float eav = ea[e];
            acc += eav;
            staged[gbase[dv >> BSH] + rank[i]] =
                make_int2((src[e] << BSH) | (dv & (BNODE - 1)), __float_as_int(eav));
        }
    }
    for (int m = 32; m >= 1; m >>= 1) acc += __shfl_xor(acc, m, 64);
    __shared__ float sh[BTHR / 64];
    int lane = t & 63, wid = t >> 6;
    if (lane == 0) sh[wid] = acc;
    __syncthreads();
    if (t == 0) {
        float s = 0.f;
        for (int i = 0; i < BTHR / 64; ++i) s += sh[i];
        unsafeAtomicAdd(&params[0], s);
    }
}

// ---------- params precompute + true bucket prefix scan (after binning) ----------
// params: [0]=ea_sum, [1]=ea_mean, [2..3]=ce layer1, [4..5]=ce layer2

__global__ void k_setup(const float* __restrict__ We1, const float* __restrict__ ae1,
                        const float* __restrict__ We2, const float* __restrict__ ae2,
                        float* __restrict__ params, const int* __restrict__ gcur,
                        int* __restrict__ gstart, int* __restrict__ rowptr) {
    int t = threadIdx.x;
    if (t < 2) {
        float c1 = 0.f, c2 = 0.f;
        for (int c = 0; c < CH; ++c) {
            c1 += We1[t * CH + c] * ae1[t * CH + c];
            c2 += We2[t * CH + c] * ae2[t * CH + c];
        }
        params[2 + t] = c1;
        params[4 + t] = c2;
        if (t == 0) params[1] = params[0] / (float)N_EDGES;
    }
    __shared__ int sh[256];
    int v[2];
    int s = 0;
    for (int j = 0; j < 2; ++j) {
        int i = t * 2 + j;
        v[j] = (i < NB2) ? (gcur[i] - i * CAP) : 0;   // per-bucket count
        s += v[j];
    }
    sh[t] = s;
    __syncthreads();
    for (int off = 1; off < 256; off <<= 1) {
        int u = (t >= off) ? sh[t - off] : 0;
        __syncthreads();
        sh[t] += u;
        __syncthreads();
    }
    int ex = sh[t] - s;   // exclusive prefix
    for (int j = 0; j < 2; ++j) {
        int i = t * 2 + j;
        if (i < NB2) { gstart[i] = ex; ex += v[j]; }
    }
    if (t == 255) {
        gstart[NB2] = N_EDGES;
        rowptr[N_NODES] = N_EDGES;
    }
}

// ---------- pass B: per-bucket local hist+scan, write rowptr + dense per-node epack ----------

__global__ void k_scatter(const int2* __restrict__ staged, const int* __restrict__ gcur,
                          const int* __restrict__ gstart,
                          int* __restrict__ rowptr, int2* __restrict__ epack) {
    __shared__ int cntl[BNODE];
    __shared__ int scanb[BNODE];
    __shared__ int cur[BNODE];
    int b = blockIdx.x, t = threadIdx.x;
    int nbase = b << BSH;
    int bcount = N_NODES - nbase;
    if (bcount > BNODE) bcount = BNODE;
    int sbase = b * CAP;
    int en = gcur[b];                 // sbase + count
    int st_true = gstart[b];
    if (t < BNODE) cntl[t] = 0;
    __syncthreads();
    for (int e = sbase + t; e < en; e += 1024)
        atomicAdd(&cntl[staged[e].x & (BNODE - 1)], 1);
    __syncthreads();
    if (t < BNODE) scanb[t] = cntl[t];
    __syncthreads();
    for (int off = 1; off < BNODE; off <<= 1) {
        int u = (t < BNODE && t >= off) ? scanb[t - off] : 0;
        __syncthreads();
        if (t < BNODE) scanb[t] += u;
        __syncthreads();
    }
    if (t < BNODE) {
        int ex = st_true + scanb[t] - cntl[t];   // exclusive, global
        cur[t] = ex;
        if (t < bcount) rowptr[nbase + t] = ex;
    }
    __syncthreads();
    for (int e = sbase + t; e < en; e += 1024) {
        int2 r = staged[e];
        int pos = atomicAdd(&cur[r.x & (BNODE - 1)], 1);
        epack[pos] = r;
    }
}

// ---------- dense: h = x @ W (LDS-tiled), plus fused asrc/adst ----------

#define COLS(ac, xv)                                                     \
    ac[0] = fmaf(xv.x, w0.x, ac[0]); ac[1] = fmaf(xv.x, w0.y, ac[1]);    \
    ac[2] = fmaf(xv.x, w0.z, ac[2]); ac[3] = fmaf(xv.x, w0.w, ac[3]);    \
    ac[0] = fmaf(xv.y, w1.x, ac[0]); ac[1] = fmaf(xv.y, w1.y, ac[1]);    \
    ac[2] = fmaf(xv.y, w1.z, ac[2]); ac[3] = fmaf(xv.y, w1.w, ac[3]);    \
    ac[0] = fmaf(xv.z, w2.x, ac[0]); ac[1] = fmaf(xv.z, w2.y, ac[1]);    \
    ac[2] = fmaf(xv.z, w2.z, ac[2]); ac[3] = fmaf(xv.z, w2.w, ac[3]);    \
    ac[0] = fmaf(xv.w, w3.x, ac[0]); ac[1] = fmaf(xv.w, w3.y, ac[1]);    \
    ac[2] = fmaf(xv.w, w3.z, ac[2]); ac[3] = fmaf(xv.w, w3.w, ac[3]);

template <int FIN>
__global__ __launch_bounds__(256)
void k_linear(const float* __restrict__ x, const float* __restrict__ W,
              const float* __restrict__ a_src, const float* __restrict__ a_dst,
              float* __restrict__ h, float* __restrict__ asrc,
              float* __restrict__ adst) {
    constexpr int PAD = FIN + 4;
    __shared__ float ws[FIN * HC];
    __shared__ float xs[64 * PAD];
    int t = threadIdx.x;
    int nbase = blockIdx.x * 64;
    int bcount = N_NODES - nbase;
    if (bcount > 64) bcount = 64;

    for (int i = t; i < FIN * HC / 4; i += 256)
        ((float4*)ws)[i] = ((const float4*)W)[i];
    const float4* xg = (const float4*)(x + (size_t)nbase * FIN);
    int nf4 = bcount * FIN / 4;
    for (int i = t; i < 64 * FIN / 4; i += 256) {
        if (i < nf4) {
            float4 v = xg[i];
            int flat = i * 4;
            int row = flat / FIN, col = flat % FIN;
            *(float4*)&xs[row * PAD + col] = v;
        }
    }
    __syncthreads();

    int cg = t & 7, np = t >> 3;
    int n0 = np * 2, n1 = n0 + 1;
    float acc0[4] = {0.f, 0.f, 0.f, 0.f};
    float acc1[4] = {0.f, 0.f, 0.f, 0.f};
#pragma unroll
    for (int k = 0; k < FIN; k += 4) {
        float4 xa = *(const float4*)&xs[n0 * PAD + k];
        float4 xb = *(const float4*)&xs[n1 * PAD + k];
        const float4* wp = (const float4*)&ws[k * HC] + cg;
        float4 w0 = wp[0], w1 = wp[8], w2 = wp[16], w3 = wp[24];
        COLS(acc0, xa)
        COLS(acc1, xb)
    }

    int hh = cg >> 2;
    float s0 = 0.f, d0 = 0.f, s1 = 0.f, d1 = 0.f;
#pragma unroll
    for (int j = 0; j < 4; ++j) {
        float av = a_src[hh * CH + (cg & 3) * 4 + j];
        float dv = a_dst[hh * CH + (cg & 3) * 4 + j];
        s0 = fmaf(acc0[j], av, s0); d0 = fmaf(acc0[j], dv, d0);
        s1 = fmaf(acc1[j], av, s1); d1 = fmaf(acc1[j], dv, d1);
    }
    s0 += __shfl_xor(s0, 1, 64); s0 += __shfl_xor(s0, 2, 64);
    d0 += __shfl_xor(d0, 1, 64); d0 += __shfl_xor(d0, 2, 64);
    s1 += __shfl_xor(s1, 1, 64); s1 += __shfl_xor(s1, 2, 64);
    d1 += __shfl_xor(d1, 1, 64); d1 += __shfl_xor(d1, 2, 64);

    if (n0 < bcount) {
        *(float4*)&h[(size_t)(nbase + n0) * HC + cg * 4] =
            make_float4(acc0[0], acc0[1], acc0[2], acc0[3]);
        if ((cg & 3) == 0) {
            asrc[(nbase + n0) * 2 + hh] = s0;
            adst[(nbase + n0) * 2 + hh] = d0;
        }
    }
    if (n1 < bcount) {
        *(float4*)&h[(size_t)(nbase + n1) * HC + cg * 4] =
            make_float4(acc1[0], acc1[1], acc1[2], acc1[3]);
        if ((cg & 3) == 0) {
            asrc[(nbase + n1) * 2 + hh] = s1;
            adst[(nbase + n1) * 2 + hh] = d1;
        }
    }
}

// ---------- fused GAT layer: 4 lanes/node, 8 channels (2x float4) per lane ----------
// NOTE: macro params named to avoid collision with float4 member tokens (.x/.y/.z/.w)

#define FMA4(ACC, WGT, VEC)                                                      \
    ACC.x = fmaf(WGT, VEC.x, ACC.x); ACC.y = fmaf(WGT, VEC.y, ACC.y);            \
    ACC.z = fmaf(WGT, VEC.z, ACC.z); ACC.w = fmaf(WGT, VEC.w, ACC.w);

__global__ void k_gat(const int* __restrict__ rowptr, const int2* __restrict__ epack,
                      const float* __restrict__ h,
                      const float* __restrict__ asrc, const float* __restrict__ adst,
                      const float* __restrict__ params, int ceoff,
                      const float* __restrict__ bias, int do_relu,
                      float* __restrict__ out) {
    int tid = blockIdx.x * blockDim.x + threadIdx.x;
    int n = tid >> 2;
    if (n >= N_NODES) return;
    int q = tid & 3, hh = q >> 1;         // lane owns channels q*8..q*8+7
    int b4 = q * 2;                        // float4 index within 8-wide row
    int st = rowptr[n], en = rowptr[n + 1];
    float ce = params[ceoff + hh];
    float adn = adst[n * 2 + hh];
    const float4* h4 = (const float4*)h;
    float4 A0 = make_float4(0.f, 0.f, 0.f, 0.f);
    float4 A1 = make_float4(0.f, 0.f, 0.f, 0.f);
    float ssum = 0.f;
    int e = st;
    for (; e + 3 < en; e += 4) {
        int2 r0 = epack[e], r1 = epack[e + 1], r2 = epack[e + 2], r3 = epack[e + 3];
        int s0 = r0.x >> BSH, s1 = r1.x >> BSH, s2 = r2.x >> BSH, s3 = r3.x >> BSH;
        float a0 = asrc[s0 * 2 + hh], a1 = asrc[s1 * 2 + hh];
        float a2 = asrc[s2 * 2 + hh], a3 = asrc[s3 * 2 + hh];
        float4 p0 = h4[s0 * 8 + b4], u0 = h4[s0 * 8 + b4 + 1];
        float4 p1 = h4[s1 * 8 + b4], u1 = h4[s1 * 8 + b4 + 1];
        float4 p2 = h4[s2 * 8 + b4], u2 = h4[s2 * 8 + b4 + 1];
        float4 p3 = h4[s3 * 8 + b4], u3 = h4[s3 * 8 + b4 + 1];
        float g0 = __expf(lrelu(a0 + adn + ce * __int_as_float(r0.y)));
        float g1 = __expf(lrelu(a1 + adn + ce * __int_as_float(r1.y)));
        float g2 = __expf(lrelu(a2 + adn + ce * __int_as_float(r2.y)));
        float g3 = __expf(lrelu(a3 + adn + ce * __int_as_float(r3.y)));
        FMA4(A0, g0, p0) FMA4(A1, g0, u0) ssum += g0;
        FMA4(A0, g1, p1) FMA4(A1, g1, u1) ssum += g1;
        FMA4(A0, g2, p2) FMA4(A1, g2, u2) ssum += g2;
        FMA4(A0, g3, p3) FMA4(A1, g3, u3) ssum += g3;
    }
    for (; e < en; ++e) {
        int2 r = epack[e];
        int sv = r.x >> BSH;
        float asv = asrc[sv * 2 + hh];
        float4 pv = h4[sv * 8 + b4], uv = h4[sv * 8 + b4 + 1];
        float gv = __expf(lrelu(asv + adn + ce * __int_as_float(r.y)));
        FMA4(A0, gv, pv) FMA4(A1, gv, uv)
        ssum += gv;
    }
    // self-loop (eattr = mean)
    float gself = __expf(lrelu(asrc[n * 2 + hh] + adn + ce * params[1]));
    float4 psf = h4[n * 8 + b4], usf = h4[n * 8 + b4 + 1];
    FMA4(A0, gself, psf) FMA4(A1, gself, usf)
    ssum += gself;
    float inv = 1.f / (ssum + 1e-16f);
    float4 bv0 = ((const float4*)bias)[b4], bv1 = ((const float4*)bias)[b4 + 1];
    float4 v0 = make_float4(A0.x * inv + bv0.x, A0.y * inv + bv0.y,
                            A0.z * inv + bv0.z, A0.w * inv + bv0.w);
    float4 v1 = make_float4(A1.x * inv + bv1.x, A1.y * inv + bv1.y,
                            A1.z * inv + bv1.z, A1.w * inv + bv1.w);
    if (do_relu) {
        v0.x = fmaxf(v0.x, 0.f); v0.y = fmaxf(v0.y, 0.f);
        v0.z = fmaxf(v0.z, 0.f); v0.w = fmaxf(v0.w, 0.f);
        v1.x = fmaxf(v1.x, 0.f); v1.y = fmaxf(v1.y, 0.f);
        v1.z = fmaxf(v1.z, 0.f); v1.w = fmaxf(v1.w, 0.f);
    }
    ((float4*)out)[n * 8 + b4] = v0;
    ((float4*)out)[n * 8 + b4 + 1] = v1;
}

// ---------- fused pooling (binary search on sorted batch) + MLP head ----------

__global__ void k_poolmlp(const float* __restrict__ feat, const int* __restrict__ batch,
                          const float* __restrict__ Wf1, const float* __restrict__ bf1,
                          const float* __restrict__ Wf2, const float* __restrict__ bf2,
                          float* __restrict__ out) {
    int g = blockIdx.x;
    __shared__ int sse[2];
    if (threadIdx.x < 2) {
        int target = g + (int)threadIdx.x;
        int lo = 0, hi = N_NODES;
        while (lo < hi) {
            int mid = (lo + hi) >> 1;
            if (batch[mid] < target) lo = mid + 1; else hi = mid;
        }
        sse[threadIdx.x] = lo;
    }
    __syncthreads();
    int st = sse[0], en = sse[1];
    int c = threadIdx.x & 31, r = threadIdx.x >> 5;  // r in 0..7
    float acc = 0.f;
    for (int n = st + r; n < en; n += 8) acc += feat[(size_t)n * HC + c];
    __shared__ float sh[8][32];
    sh[r][c] = acc;
    __syncthreads();
    __shared__ float emb[32];
    __shared__ float hid[32];
    if (threadIdx.x < 32) {
        float t = 0.f;
        for (int r2 = 0; r2 < 8; ++r2) t += sh[r2][c];
        int cnt = en - st;
        emb[c] = t / (float)(cnt > 0 ? cnt : 1);
    }
    __syncthreads();
    if (threadIdx.x < 32) {
        int j = threadIdx.x;
        float a = bf1[j];
        for (int k = 0; k < 32; ++k) a = fmaf(emb[k], Wf1[k * 32 + j], a);
        hid[j] = fmaxf(a, 0.f);
    }
    __syncthreads();
    if (threadIdx.x < 2) {
        int j = threadIdx.x;
        float o = bf2[j];
        for (int k = 0; k < 32; ++k) o = fmaf(hid[k], Wf2[k * 2 + j], o);
        out[g * 2 + j] = o;
    }
}

extern "C" void kernel_launch(void* const* d_in, const int* in_sizes, int n_in,
                              void* d_out, int out_size, void* d_ws, size_t ws_size,
                              hipStream_t stream) {
    const float* x   = (const float*)d_in[0];
    const int*   ei  = (const int*)d_in[1];
    const float* ea  = (const float*)d_in[2];
    const int* batch = (const int*)d_in[3];
    const float* W1  = (const float*)d_in[4];
    const float* as1 = (const float*)d_in[5];
    const float* ad1 = (const float*)d_in[6];
    const float* We1 = (const float*)d_in[7];
    const float* ae1 = (const float*)d_in[8];
    const float* b1  = (const float*)d_in[9];
    const float* W2  = (const float*)d_in[10];
    const float* as2 = (const float*)d_in[11];
    const float* ad2 = (const float*)d_in[12];
    const float* We2 = (const float*)d_in[13];
    const float* ae2 = (const float*)d_in[14];
    const float* b2  = (const float*)d_in[15];
    const float* Wf1 = (const float*)d_in[16];
    const float* bf1 = (const float*)d_in[17];
    const float* Wf2 = (const float*)d_in[18];
    const float* bf2 = (const float*)d_in[19];
    float* out = (float*)d_out;
    (void)in_sizes; (void)n_in; (void)out_size; (void)ws_size;

    const int* srcp = ei;
    const int* dstp = ei + N_EDGES;

    char* wsb = (char*)d_ws;
    size_t off = 0;
    auto alloc = [&](size_t bytes) -> char* {
        char* p = wsb + off;
        off = (off + bytes + 255) & ~(size_t)255;
        return p;
    };
    float* params = (float*)alloc(64);
    // region A: staged (NB2*CAP*8 = 28.8 MB), reused after k_scatter as hbuf + obuf
    char* regA = alloc((size_t)NB2 * CAP * 8 + 4096);
    int2*  staged = (int2*)regA;
    float* hbuf   = (float*)regA;
    float* obuf   = (float*)(regA + (size_t)N_NODES * HC * 4);
    int2*  epack  = (int2*)alloc((size_t)N_EDGES * 8);
    float* asrc   = (float*)alloc((size_t)N_NODES * 2 * 4);
    float* adst   = (float*)alloc((size_t)N_NODES * 2 * 4);
    int*   gstart = (int*)alloc((size_t)(NB2 + 1) * 4);
    int*   gcur   = (int*)alloc((size_t)NB2 * 4);
    int*   rowptr = (int*)alloc((size_t)(N_NODES + 1) * 4);

    const int nBlkB = (N_EDGES + EPB2 - 1) / EPB2;              // 391
    const int nBlkL = (N_NODES + 63) / 64;                      // 1563
    const int nBlkG = (N_NODES * 4 + 255) / 256;                // 1563

    // fixed-capacity bucket sort (no pre-histogram pass)
    k_init<<<1, 512, 0, stream>>>(gcur, params);
    k_bucket<<<nBlkB, BTHR, 0, stream>>>(srcp, dstp, ea, gcur, staged, params);
    k_setup<<<1, 256, 0, stream>>>(We1, ae1, We2, ae2, params, gcur, gstart, rowptr);
    k_scatter<<<NB2, 1024, 0, stream>>>(staged, gcur, gstart, rowptr, epack);

    // ----- layer 1 (hbuf/obuf overwrite staged region; stream-ordered, safe) -----
    k_linear<F_IN><<<nBlkL, 256, 0, stream>>>(x, W1, as1, ad1, hbuf, asrc, adst);
    k_gat<<<nBlkG, 256, 0, stream>>>(rowptr, epack, hbuf, asrc, adst, params, 2, b1, 1, obuf);

    // ----- layer 2 -----
    k_linear<HC><<<nBlkL, 256, 0, stream>>>(obuf, W2, as2, ad2, hbuf, asrc, adst);
    k_gat<<<nBlkG, 256, 0, stream>>>(rowptr, epack, hbuf, asrc, adst, params, 4, b2, 0, obuf);

    // ----- pool + MLP (fused; bounds via binary search on sorted batch) -----
    k_poolmlp<<<NGRAPH, 256, 0, stream>>>(obuf, batch, Wf1, bf1, Wf2, bf2, out);
}